// Round 1
// 1220.016 us; speedup vs baseline: 1.0516x; 1.0516x over previous
//
#include <hip/hip_runtime.h>
#include <hip/hip_bf16.h>
#include <cstdint>
#include <cstddef>

#define HIST    256
#define DMODEL  512
#define DINNER  1024
#define DSTATE  16
#define DTRANK  32
#define OBSDIM  4096
#define OBSOUT  448
#define ADIM    64
#define NLAYERS 4
#define MROWS   8192   // BATCH*HIST

typedef __bf16  bf16x8 __attribute__((ext_vector_type(8)));
typedef float   f32x4  __attribute__((ext_vector_type(4)));

enum { MEPI_TOK = 0, MEPI_BF16 = 1, MEPI_SPLIT = 2, MEPI_RELUB = 3 };

__device__ __forceinline__ float siluf(float x) { return x / (1.f + __expf(-x)); }
__device__ __forceinline__ float softplusf(float x) {
    return fmaxf(x, 0.f) + log1pf(__expf(-fabsf(x)));
}
__device__ __forceinline__ float bflo(unsigned u) { return __uint_as_float(u << 16); }
__device__ __forceinline__ float bfhi(unsigned u) { return __uint_as_float(u & 0xffff0000u); }

// ---------------------------------------------------------------------------
// bf16 MFMA GEMM, 128x128 tile, BK=32, double-buffered LDS, XCD-swizzled grid.
// Grid is 1-D flat = nbn*nbm blocks (nbm % 8 == 0). Decode: xcd = bid&7 owns a
// contiguous stripe of nbm/8 m-blocks and iterates its n-blocks fastest ->
// W and the A-stripe stay resident in that XCD's 4 MiB L2.
template<int EPI>
__global__ __launch_bounds__(256)
void gemm_mfma(const __hip_bfloat16* __restrict__ A, int lda,
               const __hip_bfloat16* __restrict__ W,
               float* __restrict__ Cf, int ldc,
               __hip_bfloat16* __restrict__ Cb, int ldcb,
               int coff, int N, int K, int nbn,
               const float* __restrict__ bias, const float* __restrict__ pos)
{
    __shared__ __hip_bfloat16 Asm[2][128 * 32];
    __shared__ __hip_bfloat16 Bsm[2][128 * 32];
    const int bid = blockIdx.x;
    const int xcd = bid & 7;
    const int s   = bid >> 3;
    const int n_blk = s % nbn;
    const int m_blk = xcd * ((int)(gridDim.x >> 3) / nbn) + s / nbn;
    const int m0 = m_blk * 128;
    const int n0 = n_blk * 128;

    const int tid  = threadIdx.x;
    const int lane = tid & 63;
    const int wv   = tid >> 6;
    const int wm   = (wv >> 1) << 6;
    const int wn   = (wv & 1) << 6;
    const int sr   = lane >> 2;
    const int sc   = (lane & 3) << 3;
    const int quad = lane >> 4;
    const int c16  = lane & 15;

    f32x4 acc[4][4] = {};
    const __hip_bfloat16* aptr = A + (size_t)(m0 + wv * 16 + sr) * lda + sc;
    const __hip_bfloat16* bptr = W + (size_t)(n0 + wv * 16 + sr) * K + sc;

#define STAGE(K0, BUF) { \
    __hip_bfloat16* asml = Asm[BUF] + wv * 16 * 32; \
    __hip_bfloat16* bsml = Bsm[BUF] + wv * 16 * 32; \
    __builtin_amdgcn_global_load_lds( \
        (const __attribute__((address_space(1))) void*)(aptr + (K0)), \
        (__attribute__((address_space(3))) void*)(asml), 16, 0, 0); \
    __builtin_amdgcn_global_load_lds( \
        (const __attribute__((address_space(1))) void*)(aptr + (size_t)64 * lda + (K0)), \
        (__attribute__((address_space(3))) void*)(asml + 64 * 32), 16, 0, 0); \
    __builtin_amdgcn_global_load_lds( \
        (const __attribute__((address_space(1))) void*)(bptr + (K0)), \
        (__attribute__((address_space(3))) void*)(bsml), 16, 0, 0); \
    __builtin_amdgcn_global_load_lds( \
        (const __attribute__((address_space(1))) void*)(bptr + (size_t)64 * K + (K0)), \
        (__attribute__((address_space(3))) void*)(bsml + 64 * 32), 16, 0, 0); \
    }

    STAGE(0, 0)
    __syncthreads();
    int cur = 0;
    for (int k0 = 0; k0 < K; k0 += 32) {
        if (k0 + 32 < K) STAGE(k0 + 32, cur ^ 1)

        bf16x8 af[4], bfr[4];
        #pragma unroll
        for (int i = 0; i < 4; ++i) {
            af[i]  = *(const bf16x8*)(Asm[cur] + (wm + i * 16 + c16) * 32 + quad * 8);
            bfr[i] = *(const bf16x8*)(Bsm[cur] + (wn + i * 16 + c16) * 32 + quad * 8);
        }
        #pragma unroll
        for (int i = 0; i < 4; ++i)
            #pragma unroll
            for (int j = 0; j < 4; ++j)
                acc[i][j] = __builtin_amdgcn_mfma_f32_16x16x32_bf16(af[i], bfr[j], acc[i][j], 0, 0, 0);

        __syncthreads();   // drains next-tile loads (issued before compute) + guards buffer reuse
        cur ^= 1;
    }
#undef STAGE

    #pragma unroll
    for (int i = 0; i < 4; ++i) {
        const int mbase = m0 + wm + i * 16 + quad * 4;
        #pragma unroll
        for (int j = 0; j < 4; ++j) {
            const int n = n0 + wn + j * 16 + c16;
            if (n < N) {
                #pragma unroll
                for (int r = 0; r < 4; ++r) {
                    const size_t m = mbase + r;
                    float v = acc[i][j][r];
                    if (EPI == MEPI_TOK) {
                        v += bias[n] + pos[(m & (HIST - 1)) * DMODEL + coff + n];
                        Cb[m * ldcb + coff + n] = __float2bfloat16(v);
                    } else if (EPI == MEPI_BF16) {
                        Cb[m * ldcb + n] = __float2bfloat16(v);
                    } else if (EPI == MEPI_SPLIT) {
                        if (n < DTRANK) Cf[m * 32 + n] = v;
                        else Cb[(m >> 1) * 64 + (n & 15) * 4 + (m & 1) * 2 + ((n >> 4) & 1)]
                                 = __float2bfloat16(v);
                    } else { // MEPI_RELUB
                        Cb[m * ldcb + n] = __float2bfloat16(fmaxf(v + bias[n], 0.f));
                    }
                }
            }
        }
    }
}

// ---------------------------------------------------------------------------
// f32 GEMM for W_dt (K=32): dtb = bf16(softplus(xdt @ W_dt^T + b_dt))
__global__ __launch_bounds__(256)
void gemm_f32_sp(const float* __restrict__ A, int lda,
                 const float* __restrict__ W,
                 __hip_bfloat16* __restrict__ C, int ldc,
                 int N, int K, const float* __restrict__ bias)
{
    __shared__ float As[32][68];
    __shared__ float Ws[32][68];
    const int tid = threadIdx.x;
    const int tx = tid & 15, ty = tid >> 4;
    const int m0 = blockIdx.y * 64;
    const int n0 = blockIdx.x * 64;
    const int lr = tid >> 3;
    const int lc = (tid & 7) << 2;
    float acc[4][4] = {};
    for (int k0 = 0; k0 < K; k0 += 32) {
        const float4 a0 = *(const float4*)(A + (size_t)(m0 + lr) * lda + k0 + lc);
        const float4 a1 = *(const float4*)(A + (size_t)(m0 + lr + 32) * lda + k0 + lc);
        const float4 b0 = *(const float4*)(W + (size_t)(n0 + lr) * K + k0 + lc);
        const float4 b1 = *(const float4*)(W + (size_t)(n0 + lr + 32) * K + k0 + lc);
        __syncthreads();
        As[lc+0][lr] = a0.x; As[lc+1][lr] = a0.y; As[lc+2][lr] = a0.z; As[lc+3][lr] = a0.w;
        As[lc+0][lr+32] = a1.x; As[lc+1][lr+32] = a1.y; As[lc+2][lr+32] = a1.z; As[lc+3][lr+32] = a1.w;
        Ws[lc+0][lr] = b0.x; Ws[lc+1][lr] = b0.y; Ws[lc+2][lr] = b0.z; Ws[lc+3][lr] = b0.w;
        Ws[lc+0][lr+32] = b1.x; Ws[lc+1][lr+32] = b1.y; Ws[lc+2][lr+32] = b1.z; Ws[lc+3][lr+32] = b1.w;
        __syncthreads();
        #pragma unroll
        for (int k = 0; k < 32; ++k) {
            const float4 a4 = *(const float4*)&As[k][ty << 2];
            const float4 b4 = *(const float4*)&Ws[k][tx << 2];
            const float a[4] = {a4.x, a4.y, a4.z, a4.w};
            const float b[4] = {b4.x, b4.y, b4.z, b4.w};
            #pragma unroll
            for (int i = 0; i < 4; ++i)
                #pragma unroll
                for (int j = 0; j < 4; ++j)
                    acc[i][j] = fmaf(a[i], b[j], acc[i][j]);
        }
    }
    const int mb = m0 + (ty << 2);
    const int nb = n0 + (tx << 2);
    #pragma unroll
    for (int i = 0; i < 4; ++i) {
        const size_t m = mb + i;
        #pragma unroll
        for (int j = 0; j < 4; ++j) {
            const int n = nb + j;
            C[m * ldc + n] = __float2bfloat16(softplusf(acc[i][j] + bias[n]));
        }
    }
}

// ---------------------------------------------------------------------------
__global__ __launch_bounds__(256)
void cast_bf16_kernel(const float* __restrict__ src, __hip_bfloat16* __restrict__ dst, int n4)
{
    const int i = blockIdx.x * 256 + threadIdx.x;
    if (i >= n4) return;
    const float4 v = ((const float4*)src)[i];
    union { __hip_bfloat16 h[4]; short4 s; } o;
    o.h[0] = __float2bfloat16(v.x); o.h[1] = __float2bfloat16(v.y);
    o.h[2] = __float2bfloat16(v.z); o.h[3] = __float2bfloat16(v.w);
    ((short4*)dst)[i] = o.s;
}

__global__ __launch_bounds__(256)
void cast_pad_kernel(const float* __restrict__ src, __hip_bfloat16* __restrict__ dst,
                     int nrows, int K4, int total4)
{
    const int i = blockIdx.x * 256 + threadIdx.x;
    if (i >= total4) return;
    const int row = i / K4;
    float4 v = make_float4(0.f, 0.f, 0.f, 0.f);
    if (row < nrows) v = ((const float4*)src)[i];
    union { __hip_bfloat16 h[4]; short4 s; } o;
    o.h[0] = __float2bfloat16(v.x); o.h[1] = __float2bfloat16(v.y);
    o.h[2] = __float2bfloat16(v.z); o.h[3] = __float2bfloat16(v.w);
    ((short4*)dst)[i] = o.s;
}

__global__ __launch_bounds__(256)
void embed_kernel(const int* __restrict__ actions, const float* __restrict__ act_emb,
                  const float* __restrict__ pos_emb, __hip_bfloat16* __restrict__ xb)
{
    const int idx = blockIdx.x * 256 + threadIdx.x;   // MROWS*64
    const int e = idx & 63;
    const int m = idx >> 6;
    const int l = m & (HIST - 1);
    const int b = m >> 8;
    float v = pos_emb[l * DMODEL + e];
    if (l > 0) {
        const int a = actions[b * HIST + l - 1];
        v += act_emb[a * ADIM + e];
    }
    xb[(size_t)m * DMODEL + e] = __float2bfloat16(v);
}

// xcb[m,d] = bf16(silu(conv_b[d] + sum_k conv_w[d,k]*xi[l-3+k, d]))
__global__ __launch_bounds__(256)
void conv_silu_kernel(const __hip_bfloat16* __restrict__ xzb, const float* __restrict__ cw,
                      const float* __restrict__ cb, __hip_bfloat16* __restrict__ xcb)
{
    const int idx = blockIdx.x * 256 + threadIdx.x;   // MROWS*DINNER
    const int d = idx & (DINNER - 1);
    const int m = idx >> 10;
    const int l = m & (HIST - 1);
    const float4 w = ((const float4*)cw)[d];
    const __hip_bfloat16* basep = xzb + (size_t)m * (2 * DINNER) + d;
    float acc = cb[d] + w.w * __bfloat162float(basep[0]);
    if (l >= 1) acc = fmaf(w.z, __bfloat162float(basep[-2 * DINNER]), acc);
    if (l >= 2) acc = fmaf(w.y, __bfloat162float(basep[-4 * DINNER]), acc);
    if (l >= 3) acc = fmaf(w.x, __bfloat162float(basep[-6 * DINNER]), acc);
    xcb[idx] = __float2bfloat16(siluf(acc));
}

// ---------------------------------------------------------------------------
// Selective scan v4: chunked double-buffered staging (64 steps/chunk),
// transposed [ch][step]/[state][step] LDS (stride 68, conflict-free b128 main
// loop), z via per-chunk register prefetch (no LDS), XCD-contiguous block
// swizzle, exp2-folded A. LDS 40KB -> 17.4KB (4 -> 8 blocks/CU).
__device__ __forceinline__ float dpp_add(float x, const int ctrl) {
    switch (ctrl) {
    case 0xB1:  return x + __int_as_float(__builtin_amdgcn_update_dpp(0, __float_as_int(x), 0xB1, 0xF, 0xF, true));
    case 0x4E:  return x + __int_as_float(__builtin_amdgcn_update_dpp(0, __float_as_int(x), 0x4E, 0xF, 0xF, true));
    case 0x141: return x + __int_as_float(__builtin_amdgcn_update_dpp(0, __float_as_int(x), 0x141, 0xF, 0xF, true));
    default:    return x + __int_as_float(__builtin_amdgcn_update_dpp(0, __float_as_int(x), 0x140, 0xF, 0xF, true));
    }
}

__global__ __launch_bounds__(256)
void scan_kernel(const __hip_bfloat16* __restrict__ dtb, const __hip_bfloat16* __restrict__ bcb,
                 const __hip_bfloat16* __restrict__ xcb, const __hip_bfloat16* __restrict__ zb,
                 const float* __restrict__ A_log, const float* __restrict__ D_p,
                 __hip_bfloat16* __restrict__ yb)
{
    // [buf][channel 16][step 64 + pad4] u32 {dt lo16, xc hi16} / {B lo16, C hi16}
    __shared__ unsigned sdx[2][16][68];
    __shared__ unsigned sbc[2][16][68];

    const int tid = threadIdx.x;
    const int n   = tid & 15;     // state
    const int g   = tid >> 4;     // channel within block

    // XCD-contiguous mapping: xcd k (bid&7) owns batches 4k..4k+3 so the
    // 64B lines split between d0 and d0+16 blocks stay in one L2.
    const int bid = blockIdx.x;
    const int blk = ((bid & 7) << 8) | (bid >> 3);
    const int c0  = blk * 16;
    const int b   = c0 >> 10;
    const int d0  = c0 & (DINNER - 1);
    const int d   = d0 + g;
    const size_t row0 = (size_t)b * HIST;

    // staging roles: thread t -> step sr (0..63), channel-quad sq (0..3)
    const int sr = tid >> 2;
    const int sq = tid & 3;
    const unsigned short* dtu = (const unsigned short*)dtb;
    const unsigned short* xcu = (const unsigned short*)xcb;
    const unsigned short* zu  = (const unsigned short*)zb;
    const unsigned*       bcu = (const unsigned*)bcb;

    const float Ar = -__expf(A_log[d * DSTATE + n]);
#if __has_builtin(__builtin_amdgcn_exp2f)
    const float A2 = Ar * 1.44269504089f;
#define DAEXP(x) __builtin_amdgcn_exp2f((x) * A2)
#else
#define DAEXP(x) __expf((x) * Ar)
#endif
    const float Dp = D_p[d];
    float h = 0.f;

    uint2 dv, xv; uint4 bv;
    unsigned short za[4], znx[4];

#define SLOAD(cc) { \
    const size_t rb = (row0 + (size_t)(cc) * 64 + sr) * DINNER + d0 + sq * 4; \
    dv = *(const uint2*)(dtu + rb); \
    xv = *(const uint2*)(xcu + rb); \
    bv = *(const uint4*)(bcu + row0 * 16 + (size_t)(cc) * 1024 + tid * 4); \
}
#define SWRITE(bb) { \
    const int ch = sq * 4; \
    sdx[bb][ch + 0][sr] = (dv.x & 0xffffu) | (xv.x << 16); \
    sdx[bb][ch + 1][sr] = (dv.x >> 16)     | (xv.x & 0xffff0000u); \
    sdx[bb][ch + 2][sr] = (dv.y & 0xffffu) | (xv.y << 16); \
    sdx[bb][ch + 3][sr] = (dv.y >> 16)     | (xv.y & 0xffff0000u); \
    const int e2 = (tid & 7) * 2, p2 = (tid >> 3) * 2; \
    sbc[bb][e2 + 0][p2 + 0] = bv.x; \
    sbc[bb][e2 + 0][p2 + 1] = bv.y; \
    sbc[bb][e2 + 1][p2 + 0] = bv.z; \
    sbc[bb][e2 + 1][p2 + 1] = bv.w; \
}
#define ZLOAD(cc, arr) { \
    _Pragma("unroll") \
    for (int w = 0; w < 4; ++w) \
        arr[w] = zu[(row0 + (size_t)(cc) * 64 + w * 16 + n) * (2 * DINNER) + d0 + g]; \
}
#define SSTEP(Q, R, KK) { \
    const float dt = bflo(Q), xc = bfhi(Q); \
    const float Bv = bflo(R), Cv = bfhi(R); \
    const float dA = DAEXP(dt); \
    h = fmaf(dA, h, dt * xc * Bv); \
    float ctr = h * Cv; \
    ctr = dpp_add(ctr, 0xB1); \
    ctr = dpp_add(ctr, 0x4E); \
    ctr = dpp_add(ctr, 0x141); \
    ctr = dpp_add(ctr, 0x140); \
    if (n == (KK)) yreg = ctr; \
}

    SLOAD(0)
    ZLOAD(0, za)
    SWRITE(0)
    __syncthreads();

    for (int c = 0; c < 4; ++c) {
        const int buf = c & 1;
        if (c < 3) { SLOAD(c + 1) ZLOAD(c + 1, znx) }   // issue early (T14)

        const unsigned (*sdxc)[68] = sdx[buf];
        const unsigned (*sbcc)[68] = sbc[buf];
        #pragma unroll
        for (int w = 0; w < 4; ++w) {
            float yreg = 0.f;
            #pragma unroll
            for (int jq = 0; jq < 4; ++jq) {
                const uint4 qv = *(const uint4*)&sdxc[g][w * 16 + jq * 4];
                const uint4 rv = *(const uint4*)&sbcc[n][w * 16 + jq * 4];
                SSTEP(qv.x, rv.x, jq * 4 + 0)
                SSTEP(qv.y, rv.y, jq * 4 + 1)
                SSTEP(qv.z, rv.z, jq * 4 + 2)
                SSTEP(qv.w, rv.w, jq * 4 + 3)
            }
            const float xcf = bfhi(sdxc[g][w * 16 + n]);
            const float ze  = __uint_as_float((unsigned)za[w] << 16);
            yb[(row0 + c * 64 + w * 16 + n) * DINNER + d] =
                __float2bfloat16((yreg + xcf * Dp) * siluf(ze));
        }

        if (c < 3) SWRITE((c + 1) & 1)   // write late, after compute covered latency
        __syncthreads();
        #pragma unroll
        for (int w = 0; w < 4; ++w) za[w] = znx[w];
    }
#undef SLOAD
#undef SWRITE
#undef ZLOAD
#undef SSTEP
#undef DAEXP
}

// out[m,n] = b2[n] + sum_k h[m,k]*W2[n,k]  (h in bf16)
__global__ __launch_bounds__(256)
void ffn2_kernel(const __hip_bfloat16* __restrict__ h, const float* __restrict__ W2,
                 const float* __restrict__ b2, float* __restrict__ out)
{
    const int idx = blockIdx.x * 256 + threadIdx.x;   // MROWS*32
    const int n = idx & 31;
    const int m = idx >> 5;
    if (n >= 18) return;
    const unsigned short* hr = (const unsigned short*)(h + (size_t)m * DMODEL);
    const float* wr = W2 + (size_t)n * DMODEL;
    float acc = b2[n];
    for (int k = 0; k < DMODEL; k += 8) {
        const uint4 hv = *(const uint4*)(hr + k);
        const float4 w0 = *(const float4*)(wr + k);
        const float4 w1 = *(const float4*)(wr + k + 4);
        acc = fmaf(bflo(hv.x), w0.x, acc);
        acc = fmaf(bfhi(hv.x), w0.y, acc);
        acc = fmaf(bflo(hv.y), w0.z, acc);
        acc = fmaf(bfhi(hv.y), w0.w, acc);
        acc = fmaf(bflo(hv.z), w1.x, acc);
        acc = fmaf(bfhi(hv.z), w1.y, acc);
        acc = fmaf(bflo(hv.w), w1.z, acc);
        acc = fmaf(bfhi(hv.w), w1.w, acc);
    }
    out[(size_t)m * 18 + n] = acc;
}

extern "C" void kernel_launch(void* const* d_in, const int* in_sizes, int n_in,
                              void* d_out, int out_size, void* d_ws, size_t ws_size,
                              hipStream_t stream)
{
    const float* obss    = (const float*)d_in[0];
    const int*   actions = (const int*)  d_in[1];
    const float* obs_W   = (const float*)d_in[2];
    const float* obs_b   = (const float*)d_in[3];
    const float* act_emb = (const float*)d_in[4];
    const float* pos_emb = (const float*)d_in[5];
    const float* W_in    = (const float*)d_in[6];
    const float* conv_w  = (const float*)d_in[7];
    const float* conv_b  = (const float*)d_in[8];
    const float* W_x     = (const float*)d_in[9];
    const float* W_dt    = (const float*)d_in[10];
    const float* b_dt    = (const float*)d_in[11];
    const float* A_log   = (const float*)d_in[12];
    const float* D_p     = (const float*)d_in[13];
    const float* W_out   = (const float*)d_in[14];
    const float* ffn_W1  = (const float*)d_in[15];
    const float* ffn_b1  = (const float*)d_in[16];
    const float* ffn_W2  = (const float*)d_in[17];
    const float* ffn_b2  = (const float*)d_in[18];
    float* out = (float*)d_out;

    const size_t MiB = 1024 * 1024;
    char* base = (char*)d_ws;
    __hip_bfloat16* xb    = (__hip_bfloat16*)(base);
    __hip_bfloat16* xzb   = (__hip_bfloat16*)(base + 8 * MiB);
    __hip_bfloat16* xcb   = (__hip_bfloat16*)(base + 40 * MiB);
    __hip_bfloat16* dtb   = (__hip_bfloat16*)(base + 56 * MiB);
    __hip_bfloat16* yb    = (__hip_bfloat16*)(base + 88 * MiB);
    float*          xdt   = (float*)(base + 104 * MiB);
    __hip_bfloat16* bcb   = (__hip_bfloat16*)(base + 105 * MiB);
    __hip_bfloat16* wbuf  = (__hip_bfloat16*)(base + 106 * MiB);
    __hip_bfloat16* wxb   = (__hip_bfloat16*)(base + 110 * MiB);
    __hip_bfloat16* obssb = (__hip_bfloat16*)(base + 8 * MiB);
    __hip_bfloat16* hbuf  = (__hip_bfloat16*)(base + 8 * MiB);

    // --- prologue ---
    cast_bf16_kernel<<<(MROWS * OBSDIM / 4) / 256, 256, 0, stream>>>(obss, obssb, MROWS * OBSDIM / 4);
    cast_pad_kernel<<<(512 * OBSDIM / 4) / 256, 256, 0, stream>>>(obs_W, wbuf, OBSOUT, OBSDIM / 4, 512 * OBSDIM / 4);
    embed_kernel<<<MROWS * ADIM / 256, 256, 0, stream>>>(actions, act_emb, pos_emb, xb);
    gemm_mfma<MEPI_TOK><<<4 * (MROWS / 128), 256, 0, stream>>>(
        obssb, OBSDIM, wbuf, nullptr, 0, xb, DMODEL, ADIM, OBSOUT, OBSDIM, 4, obs_b, pos_emb);

    for (int i = 0; i < NLAYERS; ++i) {
        // W_in: xzb = bf16(xb @ W_in^T), ld 2048 (xi | z)
        cast_bf16_kernel<<<(2 * DINNER * DMODEL / 4) / 256, 256, 0, stream>>>(
            W_in + (size_t)i * 2 * DINNER * DMODEL, wbuf, 2 * DINNER * DMODEL / 4);
        gemm_mfma<MEPI_BF16><<<(2 * DINNER / 128) * (MROWS / 128), 256, 0, stream>>>(
            xb, DMODEL, wbuf, nullptr, 0, xzb, 2 * DINNER, 0, 2 * DINNER, DMODEL,
            2 * DINNER / 128, nullptr, nullptr);
        conv_silu_kernel<<<MROWS * DINNER / 256, 256, 0, stream>>>(
            xzb, conv_w + (size_t)i * DINNER * 4, conv_b + (size_t)i * DINNER, xcb);
        // W_x (mfma, split): xdt = xcb @ W_x^T[:32] (f32), bcb = pair-interleaved bf16 (B,C)
        cast_pad_kernel<<<(128 * DINNER / 4) / 256, 256, 0, stream>>>(
            W_x + (size_t)i * 64 * DINNER, wxb, 64, DINNER / 4, 128 * DINNER / 4);
        gemm_mfma<MEPI_SPLIT><<<MROWS / 128, 256, 0, stream>>>(
            xcb, DINNER, wxb, xdt, 0, bcb, 0, 0, 64, DINNER, 1, nullptr, nullptr);
        // W_dt (f32, K=32, softplus): dtb (bf16)
        gemm_f32_sp<<<dim3(DINNER / 64, MROWS / 64), 256, 0, stream>>>(
            xdt, 32, W_dt + (size_t)i * DINNER * DTRANK, dtb, DINNER, DINNER, DTRANK,
            b_dt + (size_t)i * DINNER);
        scan_kernel<<<(32 * DINNER) / 16, 256, 0, stream>>>(
            dtb, bcb, xcb, xzb + DINNER, A_log + (size_t)i * DINNER * DSTATE,
            D_p + (size_t)i * DINNER, yb);
        // W_out: xb = bf16(yb @ W_out^T)
        cast_bf16_kernel<<<(DMODEL * DINNER / 4) / 256, 256, 0, stream>>>(
            W_out + (size_t)i * DMODEL * DINNER, wbuf, DMODEL * DINNER / 4);
        gemm_mfma<MEPI_BF16><<<(DMODEL / 128) * (MROWS / 128), 256, 0, stream>>>(
            yb, DINNER, wbuf, nullptr, 0, xb, DMODEL, 0, DMODEL, DINNER,
            DMODEL / 128, nullptr, nullptr);
    }

    cast_bf16_kernel<<<(DMODEL * DMODEL / 4) / 256, 256, 0, stream>>>(ffn_W1, wbuf, DMODEL * DMODEL / 4);
    gemm_mfma<MEPI_RELUB><<<(DMODEL / 128) * (MROWS / 128), 256, 0, stream>>>(
        xb, DMODEL, wbuf, nullptr, 0, hbuf, DMODEL, 0, DMODEL, DMODEL,
        DMODEL / 128, ffn_b1, nullptr);
    ffn2_kernel<<<MROWS * 32 / 256, 256, 0, stream>>>(hbuf, ffn_W2, ffn_b2, out);
}

// Round 2
// 1163.295 us; speedup vs baseline: 1.1029x; 1.0488x over previous
//
#include <hip/hip_runtime.h>
#include <hip/hip_bf16.h>
#include <cstdint>
#include <cstddef>

#define HIST    256
#define DMODEL  512
#define DINNER  1024
#define DSTATE  16
#define DTRANK  32
#define OBSDIM  4096
#define OBSOUT  448
#define ADIM    64
#define NLAYERS 4
#define MROWS   8192   // BATCH*HIST

typedef __bf16  bf16x8 __attribute__((ext_vector_type(8)));
typedef float   f32x4  __attribute__((ext_vector_type(4)));

enum { MEPI_TOK = 0, MEPI_BF16 = 1, MEPI_SPLIT = 2, MEPI_RELUB = 3 };

__device__ __forceinline__ float siluf(float x) { return x / (1.f + __expf(-x)); }
__device__ __forceinline__ float softplusf(float x) {
    return fmaxf(x, 0.f) + log1pf(__expf(-fabsf(x)));
}
__device__ __forceinline__ float bflo(unsigned u) { return __uint_as_float(u << 16); }
__device__ __forceinline__ float bfhi(unsigned u) { return __uint_as_float(u & 0xffff0000u); }

// ---------------------------------------------------------------------------
// bf16 MFMA GEMM, 128xNW tile (NW = 128 or 64), BK=32, double-buffered LDS,
// XCD-swizzled 1-D grid = nbn*nbm blocks (nbm % 8 == 0). xcd = bid&7 owns a
// contiguous stripe of nbm/8 m-blocks and iterates its n-blocks fastest.
// NW=64 halves the N-tile -> doubles grid for low-grid GEMMs so 2 blocks/CU
// co-reside and hide each other's barrier/vmcnt drain (occupancy was the
// limiter: 1 block/CU = 10.8%).
template<int EPI, int NW>
__global__ __launch_bounds__(256)
void gemm_mfma(const __hip_bfloat16* __restrict__ A, int lda,
               const __hip_bfloat16* __restrict__ W,
               float* __restrict__ Cf, int ldc,
               __hip_bfloat16* __restrict__ Cb, int ldcb,
               int coff, int N, int K, int nbn,
               const float* __restrict__ bias, const float* __restrict__ pos)
{
    constexpr int MI = (NW == 128) ? 4 : 2;   // 16-row fragments per wave (M dir)
    __shared__ __hip_bfloat16 Asm[2][128 * 32];
    __shared__ __hip_bfloat16 Bsm[2][NW * 32];
    const int bid = blockIdx.x;
    const int xcd = bid & 7;
    const int s   = bid >> 3;
    const int n_blk = s % nbn;
    const int m_blk = xcd * ((int)(gridDim.x >> 3) / nbn) + s / nbn;
    const int m0 = m_blk * 128;
    const int n0 = n_blk * NW;

    const int tid  = threadIdx.x;
    const int lane = tid & 63;
    const int wv   = tid >> 6;
    const int wm   = (NW == 128) ? ((wv >> 1) << 6) : (wv << 5);
    const int wn   = (NW == 128) ? ((wv & 1) << 6) : 0;
    const int sr   = lane >> 2;
    const int sc   = (lane & 3) << 3;
    const int quad = lane >> 4;
    const int c16  = lane & 15;

    f32x4 acc[MI][4] = {};
    const __hip_bfloat16* aptr = A + (size_t)(m0 + wv * 16 + sr) * lda + sc;
    const __hip_bfloat16* bptr = W + (size_t)(n0 + wv * 16 + sr) * K + sc;

#define STAGE(K0, BUF) { \
    __hip_bfloat16* asml = Asm[BUF] + wv * 16 * 32; \
    __hip_bfloat16* bsml = Bsm[BUF] + wv * 16 * 32; \
    __builtin_amdgcn_global_load_lds( \
        (const __attribute__((address_space(1))) void*)(aptr + (K0)), \
        (__attribute__((address_space(3))) void*)(asml), 16, 0, 0); \
    __builtin_amdgcn_global_load_lds( \
        (const __attribute__((address_space(1))) void*)(aptr + (size_t)64 * lda + (K0)), \
        (__attribute__((address_space(3))) void*)(asml + 64 * 32), 16, 0, 0); \
    __builtin_amdgcn_global_load_lds( \
        (const __attribute__((address_space(1))) void*)(bptr + (K0)), \
        (__attribute__((address_space(3))) void*)(bsml), 16, 0, 0); \
    if (NW == 128) \
        __builtin_amdgcn_global_load_lds( \
            (const __attribute__((address_space(1))) void*)(bptr + (size_t)64 * K + (K0)), \
            (__attribute__((address_space(3))) void*)(bsml + 64 * 32), 16, 0, 0); \
    }

    STAGE(0, 0)
    __syncthreads();
    int cur = 0;
    for (int k0 = 0; k0 < K; k0 += 32) {
        if (k0 + 32 < K) STAGE(k0 + 32, cur ^ 1)

        bf16x8 af[MI], bfr[4];
        #pragma unroll
        for (int i = 0; i < MI; ++i)
            af[i]  = *(const bf16x8*)(Asm[cur] + (wm + i * 16 + c16) * 32 + quad * 8);
        #pragma unroll
        for (int j = 0; j < 4; ++j)
            bfr[j] = *(const bf16x8*)(Bsm[cur] + (wn + j * 16 + c16) * 32 + quad * 8);
        #pragma unroll
        for (int i = 0; i < MI; ++i)
            #pragma unroll
            for (int j = 0; j < 4; ++j)
                acc[i][j] = __builtin_amdgcn_mfma_f32_16x16x32_bf16(af[i], bfr[j], acc[i][j], 0, 0, 0);

        __syncthreads();   // drains next-tile loads (issued before compute) + guards buffer reuse
        cur ^= 1;
    }
#undef STAGE

    #pragma unroll
    for (int i = 0; i < MI; ++i) {
        const int mbase = m0 + wm + i * 16 + quad * 4;
        #pragma unroll
        for (int j = 0; j < 4; ++j) {
            const int n = n0 + wn + j * 16 + c16;
            if (n < N) {
                #pragma unroll
                for (int r = 0; r < 4; ++r) {
                    const size_t m = mbase + r;
                    float v = acc[i][j][r];
                    if (EPI == MEPI_TOK) {
                        v += bias[n] + pos[(m & (HIST - 1)) * DMODEL + coff + n];
                        Cb[m * ldcb + coff + n] = __float2bfloat16(v);
                    } else if (EPI == MEPI_BF16) {
                        Cb[m * ldcb + n] = __float2bfloat16(v);
                    } else if (EPI == MEPI_SPLIT) {
                        if (n < DTRANK) Cf[m * 32 + n] = v;
                        else Cb[(m >> 1) * 64 + (n & 15) * 4 + (m & 1) * 2 + ((n >> 4) & 1)]
                                 = __float2bfloat16(v);
                    } else { // MEPI_RELUB
                        Cb[m * ldcb + n] = __float2bfloat16(fmaxf(v + bias[n], 0.f));
                    }
                }
            }
        }
    }
}

// ---------------------------------------------------------------------------
// f32 GEMM for W_dt (K=32): dtb = bf16(softplus(xdt @ W_dt^T + b_dt))
__global__ __launch_bounds__(256)
void gemm_f32_sp(const float* __restrict__ A, int lda,
                 const float* __restrict__ W,
                 __hip_bfloat16* __restrict__ C, int ldc,
                 int N, int K, const float* __restrict__ bias)
{
    __shared__ float As[32][68];
    __shared__ float Ws[32][68];
    const int tid = threadIdx.x;
    const int tx = tid & 15, ty = tid >> 4;
    const int m0 = blockIdx.y * 64;
    const int n0 = blockIdx.x * 64;
    const int lr = tid >> 3;
    const int lc = (tid & 7) << 2;
    float acc[4][4] = {};
    for (int k0 = 0; k0 < K; k0 += 32) {
        const float4 a0 = *(const float4*)(A + (size_t)(m0 + lr) * lda + k0 + lc);
        const float4 a1 = *(const float4*)(A + (size_t)(m0 + lr + 32) * lda + k0 + lc);
        const float4 b0 = *(const float4*)(W + (size_t)(n0 + lr) * K + k0 + lc);
        const float4 b1 = *(const float4*)(W + (size_t)(n0 + lr + 32) * K + k0 + lc);
        __syncthreads();
        As[lc+0][lr] = a0.x; As[lc+1][lr] = a0.y; As[lc+2][lr] = a0.z; As[lc+3][lr] = a0.w;
        As[lc+0][lr+32] = a1.x; As[lc+1][lr+32] = a1.y; As[lc+2][lr+32] = a1.z; As[lc+3][lr+32] = a1.w;
        Ws[lc+0][lr] = b0.x; Ws[lc+1][lr] = b0.y; Ws[lc+2][lr] = b0.z; Ws[lc+3][lr] = b0.w;
        Ws[lc+0][lr+32] = b1.x; Ws[lc+1][lr+32] = b1.y; Ws[lc+2][lr+32] = b1.z; Ws[lc+3][lr+32] = b1.w;
        __syncthreads();
        #pragma unroll
        for (int k = 0; k < 32; ++k) {
            const float4 a4 = *(const float4*)&As[k][ty << 2];
            const float4 b4 = *(const float4*)&Ws[k][tx << 2];
            const float a[4] = {a4.x, a4.y, a4.z, a4.w};
            const float b[4] = {b4.x, b4.y, b4.z, b4.w};
            #pragma unroll
            for (int i = 0; i < 4; ++i)
                #pragma unroll
                for (int j = 0; j < 4; ++j)
                    acc[i][j] = fmaf(a[i], b[j], acc[i][j]);
        }
    }
    const int mb = m0 + (ty << 2);
    const int nb = n0 + (tx << 2);
    #pragma unroll
    for (int i = 0; i < 4; ++i) {
        const size_t m = mb + i;
        #pragma unroll
        for (int j = 0; j < 4; ++j) {
            const int n = nb + j;
            C[m * ldc + n] = __float2bfloat16(softplusf(acc[i][j] + bias[n]));
        }
    }
}

// ---------------------------------------------------------------------------
__global__ __launch_bounds__(256)
void cast_bf16_kernel(const float* __restrict__ src, __hip_bfloat16* __restrict__ dst, int n4)
{
    const int i = blockIdx.x * 256 + threadIdx.x;
    if (i >= n4) return;
    const float4 v = ((const float4*)src)[i];
    union { __hip_bfloat16 h[4]; short4 s; } o;
    o.h[0] = __float2bfloat16(v.x); o.h[1] = __float2bfloat16(v.y);
    o.h[2] = __float2bfloat16(v.z); o.h[3] = __float2bfloat16(v.w);
    ((short4*)dst)[i] = o.s;
}

__global__ __launch_bounds__(256)
void cast_pad_kernel(const float* __restrict__ src, __hip_bfloat16* __restrict__ dst,
                     int nrows, int K4, int total4)
{
    const int i = blockIdx.x * 256 + threadIdx.x;
    if (i >= total4) return;
    const int row = i / K4;
    float4 v = make_float4(0.f, 0.f, 0.f, 0.f);
    if (row < nrows) v = ((const float4*)src)[i];
    union { __hip_bfloat16 h[4]; short4 s; } o;
    o.h[0] = __float2bfloat16(v.x); o.h[1] = __float2bfloat16(v.y);
    o.h[2] = __float2bfloat16(v.z); o.h[3] = __float2bfloat16(v.w);
    ((short4*)dst)[i] = o.s;
}

__global__ __launch_bounds__(256)
void embed_kernel(const int* __restrict__ actions, const float* __restrict__ act_emb,
                  const float* __restrict__ pos_emb, __hip_bfloat16* __restrict__ xb)
{
    const int idx = blockIdx.x * 256 + threadIdx.x;   // MROWS*64
    const int e = idx & 63;
    const int m = idx >> 6;
    const int l = m & (HIST - 1);
    const int b = m >> 8;
    float v = pos_emb[l * DMODEL + e];
    if (l > 0) {
        const int a = actions[b * HIST + l - 1];
        v += act_emb[a * ADIM + e];
    }
    xb[(size_t)m * DMODEL + e] = __float2bfloat16(v);
}

// xcb[m,d] = bf16(silu(conv_b[d] + sum_k conv_w[d,k]*xi[l-3+k, d]))
__global__ __launch_bounds__(256)
void conv_silu_kernel(const __hip_bfloat16* __restrict__ xzb, const float* __restrict__ cw,
                      const float* __restrict__ cb, __hip_bfloat16* __restrict__ xcb)
{
    const int idx = blockIdx.x * 256 + threadIdx.x;   // MROWS*DINNER
    const int d = idx & (DINNER - 1);
    const int m = idx >> 10;
    const int l = m & (HIST - 1);
    const float4 w = ((const float4*)cw)[d];
    const __hip_bfloat16* basep = xzb + (size_t)m * (2 * DINNER) + d;
    float acc = cb[d] + w.w * __bfloat162float(basep[0]);
    if (l >= 1) acc = fmaf(w.z, __bfloat162float(basep[-2 * DINNER]), acc);
    if (l >= 2) acc = fmaf(w.y, __bfloat162float(basep[-4 * DINNER]), acc);
    if (l >= 3) acc = fmaf(w.x, __bfloat162float(basep[-6 * DINNER]), acc);
    xcb[idx] = __float2bfloat16(siluf(acc));
}

// ---------------------------------------------------------------------------
// Selective scan v4: chunked double-buffered staging (64 steps/chunk),
// transposed [ch][step]/[state][step] LDS (stride 68, conflict-free b128 main
// loop), z via per-chunk register prefetch (no LDS), XCD-contiguous block
// swizzle, exp2-folded A. LDS 40KB -> 17.4KB.
__device__ __forceinline__ float dpp_add(float x, const int ctrl) {
    switch (ctrl) {
    case 0xB1:  return x + __int_as_float(__builtin_amdgcn_update_dpp(0, __float_as_int(x), 0xB1, 0xF, 0xF, true));
    case 0x4E:  return x + __int_as_float(__builtin_amdgcn_update_dpp(0, __float_as_int(x), 0x4E, 0xF, 0xF, true));
    case 0x141: return x + __int_as_float(__builtin_amdgcn_update_dpp(0, __float_as_int(x), 0x141, 0xF, 0xF, true));
    default:    return x + __int_as_float(__builtin_amdgcn_update_dpp(0, __float_as_int(x), 0x140, 0xF, 0xF, true));
    }
}

__global__ __launch_bounds__(256)
void scan_kernel(const __hip_bfloat16* __restrict__ dtb, const __hip_bfloat16* __restrict__ bcb,
                 const __hip_bfloat16* __restrict__ xcb, const __hip_bfloat16* __restrict__ zb,
                 const float* __restrict__ A_log, const float* __restrict__ D_p,
                 __hip_bfloat16* __restrict__ yb)
{
    // [buf][channel 16][step 64 + pad4] u32 {dt lo16, xc hi16} / {B lo16, C hi16}
    __shared__ unsigned sdx[2][16][68];
    __shared__ unsigned sbc[2][16][68];

    const int tid = threadIdx.x;
    const int n   = tid & 15;     // state
    const int g   = tid >> 4;     // channel within block

    // XCD-contiguous mapping: xcd k (bid&7) owns batches 4k..4k+3 so the
    // 64B lines split between d0 and d0+16 blocks stay in one L2.
    const int bid = blockIdx.x;
    const int blk = ((bid & 7) << 8) | (bid >> 3);
    const int c0  = blk * 16;
    const int b   = c0 >> 10;
    const int d0  = c0 & (DINNER - 1);
    const int d   = d0 + g;
    const size_t row0 = (size_t)b * HIST;

    // staging roles: thread t -> step sr (0..63), channel-quad sq (0..3)
    const int sr = tid >> 2;
    const int sq = tid & 3;
    const unsigned short* dtu = (const unsigned short*)dtb;
    const unsigned short* xcu = (const unsigned short*)xcb;
    const unsigned short* zu  = (const unsigned short*)zb;
    const unsigned*       bcu = (const unsigned*)bcb;

    const float Ar = -__expf(A_log[d * DSTATE + n]);
#if __has_builtin(__builtin_amdgcn_exp2f)
    const float A2 = Ar * 1.44269504089f;
#define DAEXP(x) __builtin_amdgcn_exp2f((x) * A2)
#else
#define DAEXP(x) __expf((x) * Ar)
#endif
    const float Dp = D_p[d];
    float h = 0.f;

    uint2 dv, xv; uint4 bv;
    unsigned short za[4], znx[4];

#define SLOAD(cc) { \
    const size_t rb = (row0 + (size_t)(cc) * 64 + sr) * DINNER + d0 + sq * 4; \
    dv = *(const uint2*)(dtu + rb); \
    xv = *(const uint2*)(xcu + rb); \
    bv = *(const uint4*)(bcu + row0 * 16 + (size_t)(cc) * 1024 + tid * 4); \
}
#define SWRITE(bb) { \
    const int ch = sq * 4; \
    sdx[bb][ch + 0][sr] = (dv.x & 0xffffu) | (xv.x << 16); \
    sdx[bb][ch + 1][sr] = (dv.x >> 16)     | (xv.x & 0xffff0000u); \
    sdx[bb][ch + 2][sr] = (dv.y & 0xffffu) | (xv.y << 16); \
    sdx[bb][ch + 3][sr] = (dv.y >> 16)     | (xv.y & 0xffff0000u); \
    const int e2 = (tid & 7) * 2, p2 = (tid >> 3) * 2; \
    sbc[bb][e2 + 0][p2 + 0] = bv.x; \
    sbc[bb][e2 + 0][p2 + 1] = bv.y; \
    sbc[bb][e2 + 1][p2 + 0] = bv.z; \
    sbc[bb][e2 + 1][p2 + 1] = bv.w; \
}
#define ZLOAD(cc, arr) { \
    _Pragma("unroll") \
    for (int w = 0; w < 4; ++w) \
        arr[w] = zu[(row0 + (size_t)(cc) * 64 + w * 16 + n) * (2 * DINNER) + d0 + g]; \
}
#define SSTEP(Q, R, KK) { \
    const float dt = bflo(Q), xc = bfhi(Q); \
    const float Bv = bflo(R), Cv = bfhi(R); \
    const float dA = DAEXP(dt); \
    h = fmaf(dA, h, dt * xc * Bv); \
    float ctr = h * Cv; \
    ctr = dpp_add(ctr, 0xB1); \
    ctr = dpp_add(ctr, 0x4E); \
    ctr = dpp_add(ctr, 0x141); \
    ctr = dpp_add(ctr, 0x140); \
    if (n == (KK)) yreg = ctr; \
}

    SLOAD(0)
    ZLOAD(0, za)
    SWRITE(0)
    __syncthreads();

    for (int c = 0; c < 4; ++c) {
        const int buf = c & 1;
        if (c < 3) { SLOAD(c + 1) ZLOAD(c + 1, znx) }   // issue early (T14)

        const unsigned (*sdxc)[68] = sdx[buf];
        const unsigned (*sbcc)[68] = sbc[buf];
        #pragma unroll
        for (int w = 0; w < 4; ++w) {
            float yreg = 0.f;
            #pragma unroll
            for (int jq = 0; jq < 4; ++jq) {
                const uint4 qv = *(const uint4*)&sdxc[g][w * 16 + jq * 4];
                const uint4 rv = *(const uint4*)&sbcc[n][w * 16 + jq * 4];
                SSTEP(qv.x, rv.x, jq * 4 + 0)
                SSTEP(qv.y, rv.y, jq * 4 + 1)
                SSTEP(qv.z, rv.z, jq * 4 + 2)
                SSTEP(qv.w, rv.w, jq * 4 + 3)
            }
            const float xcf = bfhi(sdxc[g][w * 16 + n]);
            const float ze  = __uint_as_float((unsigned)za[w] << 16);
            yb[(row0 + c * 64 + w * 16 + n) * DINNER + d] =
                __float2bfloat16((yreg + xcf * Dp) * siluf(ze));
        }

        if (c < 3) SWRITE((c + 1) & 1)   // write late, after compute covered latency
        __syncthreads();
        #pragma unroll
        for (int w = 0; w < 4; ++w) za[w] = znx[w];
    }
#undef SLOAD
#undef SWRITE
#undef ZLOAD
#undef SSTEP
#undef DAEXP
}

// out[m,n] = b2[n] + sum_k h[m,k]*W2[n,k]  (h in bf16)
__global__ __launch_bounds__(256)
void ffn2_kernel(const __hip_bfloat16* __restrict__ h, const float* __restrict__ W2,
                 const float* __restrict__ b2, float* __restrict__ out)
{
    const int idx = blockIdx.x * 256 + threadIdx.x;   // MROWS*32
    const int n = idx & 31;
    const int m = idx >> 5;
    if (n >= 18) return;
    const unsigned short* hr = (const unsigned short*)(h + (size_t)m * DMODEL);
    const float* wr = W2 + (size_t)n * DMODEL;
    float acc = b2[n];
    for (int k = 0; k < DMODEL; k += 8) {
        const uint4 hv = *(const uint4*)(hr + k);
        const float4 w0 = *(const float4*)(wr + k);
        const float4 w1 = *(const float4*)(wr + k + 4);
        acc = fmaf(bflo(hv.x), w0.x, acc);
        acc = fmaf(bfhi(hv.x), w0.y, acc);
        acc = fmaf(bflo(hv.y), w0.z, acc);
        acc = fmaf(bfhi(hv.y), w0.w, acc);
        acc = fmaf(bflo(hv.z), w1.x, acc);
        acc = fmaf(bfhi(hv.z), w1.y, acc);
        acc = fmaf(bflo(hv.w), w1.z, acc);
        acc = fmaf(bfhi(hv.w), w1.w, acc);
    }
    out[(size_t)m * 18 + n] = acc;
}

extern "C" void kernel_launch(void* const* d_in, const int* in_sizes, int n_in,
                              void* d_out, int out_size, void* d_ws, size_t ws_size,
                              hipStream_t stream)
{
    const float* obss    = (const float*)d_in[0];
    const int*   actions = (const int*)  d_in[1];
    const float* obs_W   = (const float*)d_in[2];
    const float* obs_b   = (const float*)d_in[3];
    const float* act_emb = (const float*)d_in[4];
    const float* pos_emb = (const float*)d_in[5];
    const float* W_in    = (const float*)d_in[6];
    const float* conv_w  = (const float*)d_in[7];
    const float* conv_b  = (const float*)d_in[8];
    const float* W_x     = (const float*)d_in[9];
    const float* W_dt    = (const float*)d_in[10];
    const float* b_dt    = (const float*)d_in[11];
    const float* A_log   = (const float*)d_in[12];
    const float* D_p     = (const float*)d_in[13];
    const float* W_out   = (const float*)d_in[14];
    const float* ffn_W1  = (const float*)d_in[15];
    const float* ffn_b1  = (const float*)d_in[16];
    const float* ffn_W2  = (const float*)d_in[17];
    const float* ffn_b2  = (const float*)d_in[18];
    float* out = (float*)d_out;

    const size_t MiB = 1024 * 1024;
    char* base = (char*)d_ws;
    __hip_bfloat16* xb    = (__hip_bfloat16*)(base);
    __hip_bfloat16* xzb   = (__hip_bfloat16*)(base + 8 * MiB);
    __hip_bfloat16* xcb   = (__hip_bfloat16*)(base + 40 * MiB);
    __hip_bfloat16* dtb   = (__hip_bfloat16*)(base + 56 * MiB);
    __hip_bfloat16* yb    = (__hip_bfloat16*)(base + 88 * MiB);
    float*          xdt   = (float*)(base + 104 * MiB);
    __hip_bfloat16* bcb   = (__hip_bfloat16*)(base + 105 * MiB);
    __hip_bfloat16* wbuf  = (__hip_bfloat16*)(base + 106 * MiB);
    __hip_bfloat16* wxb   = (__hip_bfloat16*)(base + 110 * MiB);
    __hip_bfloat16* obssb = (__hip_bfloat16*)(base + 8 * MiB);
    __hip_bfloat16* hbuf  = (__hip_bfloat16*)(base + 8 * MiB);

    // --- prologue ---
    cast_bf16_kernel<<<(MROWS * OBSDIM / 4) / 256, 256, 0, stream>>>(obss, obssb, MROWS * OBSDIM / 4);
    cast_pad_kernel<<<(512 * OBSDIM / 4) / 256, 256, 0, stream>>>(obs_W, wbuf, OBSOUT, OBSDIM / 4, 512 * OBSDIM / 4);
    embed_kernel<<<MROWS * ADIM / 256, 256, 0, stream>>>(actions, act_emb, pos_emb, xb);
    // NW=64: grid 512 (2 blocks/CU) to hide the per-K-step barrier drain
    gemm_mfma<MEPI_TOK, 64><<<8 * (MROWS / 128), 256, 0, stream>>>(
        obssb, OBSDIM, wbuf, nullptr, 0, xb, DMODEL, ADIM, OBSOUT, OBSDIM, 8, obs_b, pos_emb);

    for (int i = 0; i < NLAYERS; ++i) {
        // W_in: xzb = bf16(xb @ W_in^T), ld 2048 (xi | z)
        cast_bf16_kernel<<<(2 * DINNER * DMODEL / 4) / 256, 256, 0, stream>>>(
            W_in + (size_t)i * 2 * DINNER * DMODEL, wbuf, 2 * DINNER * DMODEL / 4);
        gemm_mfma<MEPI_BF16, 128><<<(2 * DINNER / 128) * (MROWS / 128), 256, 0, stream>>>(
            xb, DMODEL, wbuf, nullptr, 0, xzb, 2 * DINNER, 0, 2 * DINNER, DMODEL,
            2 * DINNER / 128, nullptr, nullptr);
        conv_silu_kernel<<<MROWS * DINNER / 256, 256, 0, stream>>>(
            xzb, conv_w + (size_t)i * DINNER * 4, conv_b + (size_t)i * DINNER, xcb);
        // W_x (mfma, split): xdt = xcb @ W_x^T[:32] (f32), bcb = pair-interleaved bf16 (B,C)
        cast_pad_kernel<<<(128 * DINNER / 4) / 256, 256, 0, stream>>>(
            W_x + (size_t)i * 64 * DINNER, wxb, 64, DINNER / 4, 128 * DINNER / 4);
        gemm_mfma<MEPI_SPLIT, 64><<<MROWS / 128, 256, 0, stream>>>(
            xcb, DINNER, wxb, xdt, 0, bcb, 0, 0, 64, DINNER, 1, nullptr, nullptr);
        // W_dt (f32, K=32, softplus): dtb (bf16)
        gemm_f32_sp<<<dim3(DINNER / 64, MROWS / 64), 256, 0, stream>>>(
            xdt, 32, W_dt + (size_t)i * DINNER * DTRANK, dtb, DINNER, DINNER, DTRANK,
            b_dt + (size_t)i * DINNER);
        scan_kernel<<<(32 * DINNER) / 16, 256, 0, stream>>>(
            dtb, bcb, xcb, xzb + DINNER, A_log + (size_t)i * DINNER * DSTATE,
            D_p + (size_t)i * DINNER, yb);
        // W_out: xb = bf16(yb @ W_out^T), NW=64 -> grid 512
        cast_bf16_kernel<<<(DMODEL * DINNER / 4) / 256, 256, 0, stream>>>(
            W_out + (size_t)i * DMODEL * DINNER, wbuf, DMODEL * DINNER / 4);
        gemm_mfma<MEPI_BF16, 64><<<(DMODEL / 64) * (MROWS / 128), 256, 0, stream>>>(
            yb, DINNER, wbuf, nullptr, 0, xb, DMODEL, 0, DMODEL, DINNER,
            DMODEL / 64, nullptr, nullptr);
    }

    cast_bf16_kernel<<<(DMODEL * DMODEL / 4) / 256, 256, 0, stream>>>(ffn_W1, wbuf, DMODEL * DMODEL / 4);
    gemm_mfma<MEPI_RELUB, 64><<<(DMODEL / 64) * (MROWS / 128), 256, 0, stream>>>(
        xb, DMODEL, wbuf, nullptr, 0, hbuf, DMODEL, 0, DMODEL, DMODEL,
        DMODEL / 64, ffn_b1, nullptr);
    ffn2_kernel<<<MROWS * 32 / 256, 256, 0, stream>>>(hbuf, ffn_W2, ffn_b2, out);
}

// Round 3
// 1143.298 us; speedup vs baseline: 1.1221x; 1.0175x over previous
//
#include <hip/hip_runtime.h>
#include <hip/hip_bf16.h>
#include <cstdint>
#include <cstddef>

#define HIST    256
#define DMODEL  512
#define DINNER  1024
#define DSTATE  16
#define DTRANK  32
#define OBSDIM  4096
#define OBSOUT  448
#define ADIM    64
#define NLAYERS 4
#define MROWS   8192   // BATCH*HIST

typedef __bf16  bf16x8 __attribute__((ext_vector_type(8)));
typedef float   f32x4  __attribute__((ext_vector_type(4)));

enum { MEPI_TOK = 0, MEPI_BF16 = 1, MEPI_SPLIT = 2, MEPI_RELUB = 3, MEPI_PART = 4 };

__device__ __forceinline__ float siluf(float x) { return x / (1.f + __expf(-x)); }
__device__ __forceinline__ float softplusf(float x) {
    return fmaxf(x, 0.f) + log1pf(__expf(-fabsf(x)));
}
__device__ __forceinline__ float bflo(unsigned u) { return __uint_as_float(u << 16); }
__device__ __forceinline__ float bfhi(unsigned u) { return __uint_as_float(u & 0xffff0000u); }

// ---------------------------------------------------------------------------
// bf16 MFMA GEMM, 128xNW tile (NW = 128 or 64), BK=32, double-buffered LDS,
// XCD-swizzled 1-D grid. Counted-vmcnt pipeline (T3/T4): next-tile
// global_load_lds stays in flight across the barriers; only the last
// iteration drains vmcnt(0). Two raw barriers per K-step: A (loads of cur
// tile visible to all) and B (all reads of cur done before anyone's next
// STAGE overwrites that buffer).
// LDS bank de-conflict: global source chunk is pre-swizzled
// (chunk ^ ((row>>2)&3)) so the linear global_load_lds dest yields an
// XOR-swizzled layout; ds_read_b128 applies the same XOR -> 8-way -> 2-way.
// MEPI_PART: split-K over 4 chunks of 256 (for the W_x projection, which
// otherwise runs 64 blocks = 25% of CUs); partials to Cf[kc][M][64] f32.
template<int EPI, int NW>
__global__ __launch_bounds__(256)
void gemm_mfma(const __hip_bfloat16* __restrict__ A, int lda,
               const __hip_bfloat16* __restrict__ W,
               float* __restrict__ Cf, int ldc,
               __hip_bfloat16* __restrict__ Cb, int ldcb,
               int coff, int N, int K, int nbn,
               const float* __restrict__ bias, const float* __restrict__ pos)
{
    constexpr int MI = (NW == 128) ? 4 : 2;   // 16-row fragments per wave (M dir)
    __shared__ __hip_bfloat16 Asm[2][128 * 32];
    __shared__ __hip_bfloat16 Bsm[2][NW * 32];
    const int bid = blockIdx.x;
    const int xcd = bid & 7;
    const int s   = bid >> 3;
    int n_blk, m_blk, kc_ = 0;
    if constexpr (EPI == MEPI_PART) {
        // grid == 256: 64 m-blocks x 4 k-chunks; same-m chunks stay on one XCD
        m_blk = xcd * 8 + (s >> 2);
        kc_   = s & 3;
        n_blk = 0;
    } else {
        n_blk = s % nbn;
        m_blk = xcd * ((int)(gridDim.x >> 3) / nbn) + s / nbn;
    }
    const int m0 = m_blk * 128;
    const int n0 = n_blk * NW;

    const int tid  = threadIdx.x;
    const int lane = tid & 63;
    const int wv   = tid >> 6;
    const int wm   = (NW == 128) ? ((wv >> 1) << 6) : (wv << 5);
    const int wn   = (NW == 128) ? ((wv & 1) << 6) : 0;
    const int sr   = lane >> 2;
    const int scs  = (((lane & 3) ^ ((lane >> 4) & 3)) << 3);  // pre-swizzled source chunk
    const int quad = lane >> 4;
    const int c16  = lane & 15;

    f32x4 acc[MI][4] = {};
    const __hip_bfloat16* aptr = A + (size_t)(m0 + wv * 16 + sr) * lda + scs + kc_ * 256;
    const __hip_bfloat16* bptr = W + (size_t)(n0 + wv * 16 + sr) * K + scs;

#define STAGE(K0, BUF) { \
    __hip_bfloat16* asml = Asm[BUF] + wv * 16 * 32; \
    __hip_bfloat16* bsml = Bsm[BUF] + wv * 16 * 32; \
    __builtin_amdgcn_global_load_lds( \
        (const __attribute__((address_space(1))) void*)(aptr + (K0)), \
        (__attribute__((address_space(3))) void*)(asml), 16, 0, 0); \
    __builtin_amdgcn_global_load_lds( \
        (const __attribute__((address_space(1))) void*)(aptr + (size_t)64 * lda + (K0)), \
        (__attribute__((address_space(3))) void*)(asml + 64 * 32), 16, 0, 0); \
    __builtin_amdgcn_global_load_lds( \
        (const __attribute__((address_space(1))) void*)(bptr + (K0)), \
        (__attribute__((address_space(3))) void*)(bsml), 16, 0, 0); \
    if (NW == 128) \
        __builtin_amdgcn_global_load_lds( \
            (const __attribute__((address_space(1))) void*)(bptr + (size_t)64 * K + (K0)), \
            (__attribute__((address_space(3))) void*)(bsml + 64 * 32), 16, 0, 0); \
    }

    STAGE(0, 0)
    int cur = 0;
    for (int k0 = 0; k0 < K; k0 += 32) {
        if (k0 + 32 < K) {
            STAGE(k0 + 32, cur ^ 1)
            // keep the next tile's loads in flight; wait only for cur's
            if constexpr (NW == 128) asm volatile("s_waitcnt vmcnt(4)" ::: "memory");
            else                     asm volatile("s_waitcnt vmcnt(3)" ::: "memory");
        } else {
            asm volatile("s_waitcnt vmcnt(0)" ::: "memory");
        }
        __builtin_amdgcn_s_barrier();            // A: everyone's cur-tile loads done
        __builtin_amdgcn_sched_barrier(0);

        bf16x8 af[MI], bfr[4];
        #pragma unroll
        for (int i = 0; i < MI; ++i) {
            const int csw = ((quad ^ ((c16 >> 2) & 3)) << 3);
            af[i]  = *(const bf16x8*)(Asm[cur] + (wm + i * 16 + c16) * 32 + csw);
        }
        #pragma unroll
        for (int j = 0; j < 4; ++j) {
            const int csw = ((quad ^ ((c16 >> 2) & 3)) << 3);
            bfr[j] = *(const bf16x8*)(Bsm[cur] + (wn + j * 16 + c16) * 32 + csw);
        }
        #pragma unroll
        for (int i = 0; i < MI; ++i)
            #pragma unroll
            for (int j = 0; j < 4; ++j)
                acc[i][j] = __builtin_amdgcn_mfma_f32_16x16x32_bf16(af[i], bfr[j], acc[i][j], 0, 0, 0);

        __builtin_amdgcn_sched_barrier(0);
        __builtin_amdgcn_s_barrier();            // B: all reads of cur done -> buffer reusable
        cur ^= 1;
    }
#undef STAGE

    #pragma unroll
    for (int i = 0; i < MI; ++i) {
        const int mbase = m0 + wm + i * 16 + quad * 4;
        #pragma unroll
        for (int j = 0; j < 4; ++j) {
            const int n = n0 + wn + j * 16 + c16;
            if (n < N) {
                #pragma unroll
                for (int r = 0; r < 4; ++r) {
                    const size_t m = mbase + r;
                    float v = acc[i][j][r];
                    if (EPI == MEPI_TOK) {
                        v += bias[n] + pos[(m & (HIST - 1)) * DMODEL + coff + n];
                        Cb[m * ldcb + coff + n] = __float2bfloat16(v);
                    } else if (EPI == MEPI_BF16) {
                        Cb[m * ldcb + n] = __float2bfloat16(v);
                    } else if (EPI == MEPI_SPLIT) {
                        if (n < DTRANK) Cf[m * 32 + n] = v;
                        else Cb[(m >> 1) * 64 + (n & 15) * 4 + (m & 1) * 2 + ((n >> 4) & 1)]
                                 = __float2bfloat16(v);
                    } else if (EPI == MEPI_PART) {
                        Cf[((size_t)kc_ * MROWS + m) * 64 + n] = v;
                    } else { // MEPI_RELUB
                        Cb[m * ldcb + n] = __float2bfloat16(fmaxf(v + bias[n], 0.f));
                    }
                }
            }
        }
    }
}

// sums the 4 split-K partials; n<32 -> xdt (f32), n>=32 -> bcb (packed bf16)
__global__ __launch_bounds__(256)
void combine_split_kernel(const float* __restrict__ p, float* __restrict__ xdt,
                          __hip_bfloat16* __restrict__ bcb)
{
    const int idx = blockIdx.x * 256 + threadIdx.x;     // MROWS*16
    const int m  = idx >> 4;
    const int n4 = (idx & 15) << 2;
    const float4 a = *(const float4*)(p + (size_t)m * 64 + n4);
    const float4 b = *(const float4*)(p + ((size_t)MROWS + m) * 64 + n4);
    const float4 c = *(const float4*)(p + ((size_t)2 * MROWS + m) * 64 + n4);
    const float4 d = *(const float4*)(p + ((size_t)3 * MROWS + m) * 64 + n4);
    const float v[4] = { a.x + b.x + c.x + d.x, a.y + b.y + c.y + d.y,
                         a.z + b.z + c.z + d.z, a.w + b.w + c.w + d.w };
    if (n4 < 32) {
        *(float4*)(xdt + (size_t)m * 32 + n4) = make_float4(v[0], v[1], v[2], v[3]);
    } else {
        #pragma unroll
        for (int j = 0; j < 4; ++j) {
            const int n = n4 + j;
            bcb[(m >> 1) * 64 + (n & 15) * 4 + (m & 1) * 2 + ((n >> 4) & 1)]
                = __float2bfloat16(v[j]);
        }
    }
}

// ---------------------------------------------------------------------------
// f32 GEMM for W_dt (K=32): dtb = bf16(softplus(xdt @ W_dt^T + b_dt))
__global__ __launch_bounds__(256)
void gemm_f32_sp(const float* __restrict__ A, int lda,
                 const float* __restrict__ W,
                 __hip_bfloat16* __restrict__ C, int ldc,
                 int N, int K, const float* __restrict__ bias)
{
    __shared__ float As[32][68];
    __shared__ float Ws[32][68];
    const int tid = threadIdx.x;
    const int tx = tid & 15, ty = tid >> 4;
    const int m0 = blockIdx.y * 64;
    const int n0 = blockIdx.x * 64;
    const int lr = tid >> 3;
    const int lc = (tid & 7) << 2;
    float acc[4][4] = {};
    for (int k0 = 0; k0 < K; k0 += 32) {
        const float4 a0 = *(const float4*)(A + (size_t)(m0 + lr) * lda + k0 + lc);
        const float4 a1 = *(const float4*)(A + (size_t)(m0 + lr + 32) * lda + k0 + lc);
        const float4 b0 = *(const float4*)(W + (size_t)(n0 + lr) * K + k0 + lc);
        const float4 b1 = *(const float4*)(W + (size_t)(n0 + lr + 32) * K + k0 + lc);
        __syncthreads();
        As[lc+0][lr] = a0.x; As[lc+1][lr] = a0.y; As[lc+2][lr] = a0.z; As[lc+3][lr] = a0.w;
        As[lc+0][lr+32] = a1.x; As[lc+1][lr+32] = a1.y; As[lc+2][lr+32] = a1.z; As[lc+3][lr+32] = a1.w;
        Ws[lc+0][lr] = b0.x; Ws[lc+1][lr] = b0.y; Ws[lc+2][lr] = b0.z; Ws[lc+3][lr] = b0.w;
        Ws[lc+0][lr+32] = b1.x; Ws[lc+1][lr+32] = b1.y; Ws[lc+2][lr+32] = b1.z; Ws[lc+3][lr+32] = b1.w;
        __syncthreads();
        #pragma unroll
        for (int k = 0; k < 32; ++k) {
            const float4 a4 = *(const float4*)&As[k][ty << 2];
            const float4 b4 = *(const float4*)&Ws[k][tx << 2];
            const float a[4] = {a4.x, a4.y, a4.z, a4.w};
            const float b[4] = {b4.x, b4.y, b4.z, b4.w};
            #pragma unroll
            for (int i = 0; i < 4; ++i)
                #pragma unroll
                for (int j = 0; j < 4; ++j)
                    acc[i][j] = fmaf(a[i], b[j], acc[i][j]);
        }
    }
    const int mb = m0 + (ty << 2);
    const int nb = n0 + (tx << 2);
    #pragma unroll
    for (int i = 0; i < 4; ++i) {
        const size_t m = mb + i;
        #pragma unroll
        for (int j = 0; j < 4; ++j) {
            const int n = nb + j;
            C[m * ldc + n] = __float2bfloat16(softplusf(acc[i][j] + bias[n]));
        }
    }
}

// ---------------------------------------------------------------------------
__global__ __launch_bounds__(256)
void cast_bf16_kernel(const float* __restrict__ src, __hip_bfloat16* __restrict__ dst, int n4)
{
    const int i = blockIdx.x * 256 + threadIdx.x;
    if (i >= n4) return;
    const float4 v = ((const float4*)src)[i];
    union { __hip_bfloat16 h[4]; short4 s; } o;
    o.h[0] = __float2bfloat16(v.x); o.h[1] = __float2bfloat16(v.y);
    o.h[2] = __float2bfloat16(v.z); o.h[3] = __float2bfloat16(v.w);
    ((short4*)dst)[i] = o.s;
}

__global__ __launch_bounds__(256)
void cast_pad_kernel(const float* __restrict__ src, __hip_bfloat16* __restrict__ dst,
                     int nrows, int K4, int total4)
{
    const int i = blockIdx.x * 256 + threadIdx.x;
    if (i >= total4) return;
    const int row = i / K4;
    float4 v = make_float4(0.f, 0.f, 0.f, 0.f);
    if (row < nrows) v = ((const float4*)src)[i];
    union { __hip_bfloat16 h[4]; short4 s; } o;
    o.h[0] = __float2bfloat16(v.x); o.h[1] = __float2bfloat16(v.y);
    o.h[2] = __float2bfloat16(v.z); o.h[3] = __float2bfloat16(v.w);
    ((short4*)dst)[i] = o.s;
}

__global__ __launch_bounds__(256)
void embed_kernel(const int* __restrict__ actions, const float* __restrict__ act_emb,
                  const float* __restrict__ pos_emb, __hip_bfloat16* __restrict__ xb)
{
    const int idx = blockIdx.x * 256 + threadIdx.x;   // MROWS*64
    const int e = idx & 63;
    const int m = idx >> 6;
    const int l = m & (HIST - 1);
    const int b = m >> 8;
    float v = pos_emb[l * DMODEL + e];
    if (l > 0) {
        const int a = actions[b * HIST + l - 1];
        v += act_emb[a * ADIM + e];
    }
    xb[(size_t)m * DMODEL + e] = __float2bfloat16(v);
}

// xcb[m,d] = bf16(silu(conv_b[d] + sum_k conv_w[d,k]*xi[l-3+k, d]))
__global__ __launch_bounds__(256)
void conv_silu_kernel(const __hip_bfloat16* __restrict__ xzb, const float* __restrict__ cw,
                      const float* __restrict__ cb, __hip_bfloat16* __restrict__ xcb)
{
    const int idx = blockIdx.x * 256 + threadIdx.x;   // MROWS*DINNER
    const int d = idx & (DINNER - 1);
    const int m = idx >> 10;
    const int l = m & (HIST - 1);
    const float4 w = ((const float4*)cw)[d];
    const __hip_bfloat16* basep = xzb + (size_t)m * (2 * DINNER) + d;
    float acc = cb[d] + w.w * __bfloat162float(basep[0]);
    if (l >= 1) acc = fmaf(w.z, __bfloat162float(basep[-2 * DINNER]), acc);
    if (l >= 2) acc = fmaf(w.y, __bfloat162float(basep[-4 * DINNER]), acc);
    if (l >= 3) acc = fmaf(w.x, __bfloat162float(basep[-6 * DINNER]), acc);
    xcb[idx] = __float2bfloat16(siluf(acc));
}

// ---------------------------------------------------------------------------
// Selective scan v5: chunked double-buffered staging, transposed LDS,
// z register prefetch, XCD swizzle, exp2-folded A, fused single-instruction
// DPP butterfly adds (v_add_f32_dpp).
#define DPPA(x, CTRL) { float _t; \
    asm("v_add_f32_dpp %0, %1, %1 " CTRL " row_mask:0xf bank_mask:0xf" \
        : "=v"(_t) : "v"(x)); x = _t; }

__global__ __launch_bounds__(256)
void scan_kernel(const __hip_bfloat16* __restrict__ dtb, const __hip_bfloat16* __restrict__ bcb,
                 const __hip_bfloat16* __restrict__ xcb, const __hip_bfloat16* __restrict__ zb,
                 const float* __restrict__ A_log, const float* __restrict__ D_p,
                 __hip_bfloat16* __restrict__ yb)
{
    // [buf][channel 16][step 64 + pad4] u32 {dt lo16, xc hi16} / {B lo16, C hi16}
    __shared__ unsigned sdx[2][16][68];
    __shared__ unsigned sbc[2][16][68];

    const int tid = threadIdx.x;
    const int n   = tid & 15;     // state
    const int g   = tid >> 4;     // channel within block

    const int bid = blockIdx.x;
    const int blk = ((bid & 7) << 8) | (bid >> 3);
    const int c0  = blk * 16;
    const int b   = c0 >> 10;
    const int d0  = c0 & (DINNER - 1);
    const int d   = d0 + g;
    const size_t row0 = (size_t)b * HIST;

    const int sr = tid >> 2;
    const int sq = tid & 3;
    const unsigned short* dtu = (const unsigned short*)dtb;
    const unsigned short* xcu = (const unsigned short*)xcb;
    const unsigned short* zu  = (const unsigned short*)zb;
    const unsigned*       bcu = (const unsigned*)bcb;

    const float Ar = -__expf(A_log[d * DSTATE + n]);
#if __has_builtin(__builtin_amdgcn_exp2f)
    const float A2 = Ar * 1.44269504089f;
#define DAEXP(x) __builtin_amdgcn_exp2f((x) * A2)
#else
#define DAEXP(x) __expf((x) * Ar)
#endif
    const float Dp = D_p[d];
    float h = 0.f;

    uint2 dv, xv; uint4 bv;
    unsigned short za[4], znx[4];

#define SLOAD(cc) { \
    const size_t rb = (row0 + (size_t)(cc) * 64 + sr) * DINNER + d0 + sq * 4; \
    dv = *(const uint2*)(dtu + rb); \
    xv = *(const uint2*)(xcu + rb); \
    bv = *(const uint4*)(bcu + row0 * 16 + (size_t)(cc) * 1024 + tid * 4); \
}
#define SWRITE(bb) { \
    const int ch = sq * 4; \
    sdx[bb][ch + 0][sr] = (dv.x & 0xffffu) | (xv.x << 16); \
    sdx[bb][ch + 1][sr] = (dv.x >> 16)     | (xv.x & 0xffff0000u); \
    sdx[bb][ch + 2][sr] = (dv.y & 0xffffu) | (xv.y << 16); \
    sdx[bb][ch + 3][sr] = (dv.y >> 16)     | (xv.y & 0xffff0000u); \
    const int e2 = (tid & 7) * 2, p2 = (tid >> 3) * 2; \
    sbc[bb][e2 + 0][p2 + 0] = bv.x; \
    sbc[bb][e2 + 0][p2 + 1] = bv.y; \
    sbc[bb][e2 + 1][p2 + 0] = bv.z; \
    sbc[bb][e2 + 1][p2 + 1] = bv.w; \
}
#define ZLOAD(cc, arr) { \
    _Pragma("unroll") \
    for (int w = 0; w < 4; ++w) \
        arr[w] = zu[(row0 + (size_t)(cc) * 64 + w * 16 + n) * (2 * DINNER) + d0 + g]; \
}
#define SSTEP(Q, R, KK) { \
    const float dt = bflo(Q), xc = bfhi(Q); \
    const float Bv = bflo(R), Cv = bfhi(R); \
    const float dA = DAEXP(dt); \
    h = fmaf(dA, h, dt * xc * Bv); \
    float ctr = h * Cv; \
    DPPA(ctr, "quad_perm:[1,0,3,2]") \
    DPPA(ctr, "quad_perm:[2,3,0,1]") \
    DPPA(ctr, "row_half_mirror") \
    DPPA(ctr, "row_mirror") \
    if (n == (KK)) yreg = ctr; \
}

    SLOAD(0)
    ZLOAD(0, za)
    SWRITE(0)
    __syncthreads();

    for (int c = 0; c < 4; ++c) {
        const int buf = c & 1;
        if (c < 3) { SLOAD(c + 1) ZLOAD(c + 1, znx) }   // issue early (T14)

        const unsigned (*sdxc)[68] = sdx[buf];
        const unsigned (*sbcc)[68] = sbc[buf];
        #pragma unroll
        for (int w = 0; w < 4; ++w) {
            float yreg = 0.f;
            #pragma unroll
            for (int jq = 0; jq < 4; ++jq) {
                const uint4 qv = *(const uint4*)&sdxc[g][w * 16 + jq * 4];
                const uint4 rv = *(const uint4*)&sbcc[n][w * 16 + jq * 4];
                SSTEP(qv.x, rv.x, jq * 4 + 0)
                SSTEP(qv.y, rv.y, jq * 4 + 1)
                SSTEP(qv.z, rv.z, jq * 4 + 2)
                SSTEP(qv.w, rv.w, jq * 4 + 3)
            }
            const float xcf = bfhi(sdxc[g][w * 16 + n]);
            const float ze  = __uint_as_float((unsigned)za[w] << 16);
            yb[(row0 + c * 64 + w * 16 + n) * DINNER + d] =
                __float2bfloat16((yreg + xcf * Dp) * siluf(ze));
        }

        if (c < 3) SWRITE((c + 1) & 1)   // write late, after compute covered latency
        __syncthreads();
        #pragma unroll
        for (int w = 0; w < 4; ++w) za[w] = znx[w];
    }
#undef SLOAD
#undef SWRITE
#undef ZLOAD
#undef SSTEP
#undef DAEXP
}

// out[m,n] = b2[n] + sum_k h[m,k]*W2[n,k]  (h in bf16)
__global__ __launch_bounds__(256)
void ffn2_kernel(const __hip_bfloat16* __restrict__ h, const float* __restrict__ W2,
                 const float* __restrict__ b2, float* __restrict__ out)
{
    const int idx = blockIdx.x * 256 + threadIdx.x;   // MROWS*32
    const int n = idx & 31;
    const int m = idx >> 5;
    if (n >= 18) return;
    const unsigned short* hr = (const unsigned short*)(h + (size_t)m * DMODEL);
    const float* wr = W2 + (size_t)n * DMODEL;
    float acc = b2[n];
    for (int k = 0; k < DMODEL; k += 8) {
        const uint4 hv = *(const uint4*)(hr + k);
        const float4 w0 = *(const float4*)(wr + k);
        const float4 w1 = *(const float4*)(wr + k + 4);
        acc = fmaf(bflo(hv.x), w0.x, acc);
        acc = fmaf(bfhi(hv.x), w0.y, acc);
        acc = fmaf(bflo(hv.y), w0.z, acc);
        acc = fmaf(bfhi(hv.y), w0.w, acc);
        acc = fmaf(bflo(hv.z), w1.x, acc);
        acc = fmaf(bfhi(hv.z), w1.y, acc);
        acc = fmaf(bflo(hv.w), w1.z, acc);
        acc = fmaf(bfhi(hv.w), w1.w, acc);
    }
    out[(size_t)m * 18 + n] = acc;
}

extern "C" void kernel_launch(void* const* d_in, const int* in_sizes, int n_in,
                              void* d_out, int out_size, void* d_ws, size_t ws_size,
                              hipStream_t stream)
{
    const float* obss    = (const float*)d_in[0];
    const int*   actions = (const int*)  d_in[1];
    const float* obs_W   = (const float*)d_in[2];
    const float* obs_b   = (const float*)d_in[3];
    const float* act_emb = (const float*)d_in[4];
    const float* pos_emb = (const float*)d_in[5];
    const float* W_in    = (const float*)d_in[6];
    const float* conv_w  = (const float*)d_in[7];
    const float* conv_b  = (const float*)d_in[8];
    const float* W_x     = (const float*)d_in[9];
    const float* W_dt    = (const float*)d_in[10];
    const float* b_dt    = (const float*)d_in[11];
    const float* A_log   = (const float*)d_in[12];
    const float* D_p     = (const float*)d_in[13];
    const float* W_out   = (const float*)d_in[14];
    const float* ffn_W1  = (const float*)d_in[15];
    const float* ffn_b1  = (const float*)d_in[16];
    const float* ffn_W2  = (const float*)d_in[17];
    const float* ffn_b2  = (const float*)d_in[18];
    float* out = (float*)d_out;

    const size_t MiB = 1024 * 1024;
    char* base = (char*)d_ws;
    __hip_bfloat16* xb    = (__hip_bfloat16*)(base);
    __hip_bfloat16* xzb   = (__hip_bfloat16*)(base + 8 * MiB);
    __hip_bfloat16* xcb   = (__hip_bfloat16*)(base + 40 * MiB);
    __hip_bfloat16* dtb   = (__hip_bfloat16*)(base + 56 * MiB);
    __hip_bfloat16* yb    = (__hip_bfloat16*)(base + 88 * MiB);
    float*          xdt   = (float*)(base + 104 * MiB);
    __hip_bfloat16* bcb   = (__hip_bfloat16*)(base + 105 * MiB);
    __hip_bfloat16* wbuf  = (__hip_bfloat16*)(base + 106 * MiB);
    __hip_bfloat16* wxb   = (__hip_bfloat16*)(base + 110 * MiB);
    float*          xdtp  = (float*)(base + 112 * MiB);          // 4 x 2 MiB split-K partials
    __hip_bfloat16* obssb = (__hip_bfloat16*)(base + 8 * MiB);
    __hip_bfloat16* hbuf  = (__hip_bfloat16*)(base + 8 * MiB);

    // --- prologue ---
    cast_bf16_kernel<<<(MROWS * OBSDIM / 4) / 256, 256, 0, stream>>>(obss, obssb, MROWS * OBSDIM / 4);
    cast_pad_kernel<<<(512 * OBSDIM / 4) / 256, 256, 0, stream>>>(obs_W, wbuf, OBSOUT, OBSDIM / 4, 512 * OBSDIM / 4);
    embed_kernel<<<MROWS * ADIM / 256, 256, 0, stream>>>(actions, act_emb, pos_emb, xb);
    gemm_mfma<MEPI_TOK, 64><<<8 * (MROWS / 128), 256, 0, stream>>>(
        obssb, OBSDIM, wbuf, nullptr, 0, xb, DMODEL, ADIM, OBSOUT, OBSDIM, 8, obs_b, pos_emb);

    for (int i = 0; i < NLAYERS; ++i) {
        // W_in: xzb = bf16(xb @ W_in^T), ld 2048 (xi | z)
        cast_bf16_kernel<<<(2 * DINNER * DMODEL / 4) / 256, 256, 0, stream>>>(
            W_in + (size_t)i * 2 * DINNER * DMODEL, wbuf, 2 * DINNER * DMODEL / 4);
        gemm_mfma<MEPI_BF16, 128><<<(2 * DINNER / 128) * (MROWS / 128), 256, 0, stream>>>(
            xb, DMODEL, wbuf, nullptr, 0, xzb, 2 * DINNER, 0, 2 * DINNER, DMODEL,
            2 * DINNER / 128, nullptr, nullptr);
        conv_silu_kernel<<<MROWS * DINNER / 256, 256, 0, stream>>>(
            xzb, conv_w + (size_t)i * DINNER * 4, conv_b + (size_t)i * DINNER, xcb);
        // W_x: split-K=4 partials then combine into xdt (f32) + bcb (packed bf16)
        cast_pad_kernel<<<(128 * DINNER / 4) / 256, 256, 0, stream>>>(
            W_x + (size_t)i * 64 * DINNER, wxb, 64, DINNER / 4, 128 * DINNER / 4);
        gemm_mfma<MEPI_PART, 64><<<256, 256, 0, stream>>>(
            xcb, DINNER, wxb, xdtp, 0, nullptr, 0, 0, 64, 256, 1, nullptr, nullptr);
        combine_split_kernel<<<MROWS * 16 / 256, 256, 0, stream>>>(xdtp, xdt, bcb);
        // W_dt (f32, K=32, softplus): dtb (bf16)
        gemm_f32_sp<<<dim3(DINNER / 64, MROWS / 64), 256, 0, stream>>>(
            xdt, 32, W_dt + (size_t)i * DINNER * DTRANK, dtb, DINNER, DINNER, DTRANK,
            b_dt + (size_t)i * DINNER);
        scan_kernel<<<(32 * DINNER) / 16, 256, 0, stream>>>(
            dtb, bcb, xcb, xzb + DINNER, A_log + (size_t)i * DINNER * DSTATE,
            D_p + (size_t)i * DINNER, yb);
        // W_out: xb = bf16(yb @ W_out^T)
        cast_bf16_kernel<<<(DMODEL * DINNER / 4) / 256, 256, 0, stream>>>(
            W_out + (size_t)i * DMODEL * DINNER, wbuf, DMODEL * DINNER / 4);
        gemm_mfma<MEPI_BF16, 64><<<(DMODEL / 64) * (MROWS / 128), 256, 0, stream>>>(
            yb, DINNER, wbuf, nullptr, 0, xb, DMODEL, 0, DMODEL, DINNER,
            DMODEL / 64, nullptr, nullptr);
    }

    cast_bf16_kernel<<<(DMODEL * DMODEL / 4) / 256, 256, 0, stream>>>(ffn_W1, wbuf, DMODEL * DMODEL / 4);
    gemm_mfma<MEPI_RELUB, 64><<<(DMODEL / 64) * (MROWS / 128), 256, 0, stream>>>(
        xb, DMODEL, wbuf, nullptr, 0, hbuf, DMODEL, 0, DMODEL, DMODEL,
        DMODEL / 64, ffn_b1, nullptr);
    ffn2_kernel<<<MROWS * 32 / 256, 256, 0, stream>>>(hbuf, ffn_W2, ffn_b2, out);
}

// Round 4
// 1138.204 us; speedup vs baseline: 1.1272x; 1.0045x over previous
//
#include <hip/hip_runtime.h>
#include <hip/hip_bf16.h>
#include <cstdint>
#include <cstddef>

#define HIST    256
#define DMODEL  512
#define DINNER  1024
#define DSTATE  16
#define DTRANK  32
#define OBSDIM  4096
#define OBSOUT  448
#define ADIM    64
#define NLAYERS 4
#define MROWS   8192   // BATCH*HIST

typedef __bf16  bf16x8 __attribute__((ext_vector_type(8)));
typedef float   f32x4  __attribute__((ext_vector_type(4)));

enum { MEPI_TOK = 0, MEPI_BF16 = 1, MEPI_SPLIT = 2, MEPI_RELUB = 3, MEPI_PART = 4 };

__device__ __forceinline__ float siluf(float x) { return x / (1.f + __expf(-x)); }
__device__ __forceinline__ float softplusf(float x) {
    return fmaxf(x, 0.f) + log1pf(__expf(-fabsf(x)));
}
__device__ __forceinline__ float bflo(unsigned u) { return __uint_as_float(u << 16); }
__device__ __forceinline__ float bfhi(unsigned u) { return __uint_as_float(u & 0xffff0000u); }

// ---------------------------------------------------------------------------
// bf16 MFMA GEMM, 128xNW tile (NW = 128 or 64), BK=32, FOUR-buffer LDS with
// prefetch distance 3 (global-load latency ~900cy amortized /3; R3 showed the
// loop was latency-bound at depth 1: 740cy/K-step vs ~150cy MFMA).
// Two raw barriers per K-step (same proven structure as R3):
//   A: everyone's cur-tile loads done;  B: all reads of cur done before the
//   next STAGE (issued in iter+1, targeting buf (i+4)&3 == (i)&3... distance-3
//   with 4 buffers means iter i stages buf[(i+3)&3] = buf[(i-1)&3], whose
//   reads completed before iter i-1's barrier B).
// Main loop waits vmcnt(3L) so 3 tiles stay in flight; peeled tail at 2L,L,0.
// MEPI_PART: split-K over 4 chunks of 256 for the W_x projection.
template<int EPI, int NW>
__global__ __launch_bounds__(256)
void gemm_mfma(const __hip_bfloat16* __restrict__ A, int lda,
               const __hip_bfloat16* __restrict__ W,
               float* __restrict__ Cf, int ldc,
               __hip_bfloat16* __restrict__ Cb, int ldcb,
               int coff, int N, int K, int nbn,
               const float* __restrict__ bias, const float* __restrict__ pos)
{
    constexpr int MI = (NW == 128) ? 4 : 2;   // 16-row fragments per wave (M dir)
    __shared__ __hip_bfloat16 Asm[4][128 * 32];
    __shared__ __hip_bfloat16 Bsm[4][NW * 32];
    const int bid = blockIdx.x;
    const int xcd = bid & 7;
    const int s   = bid >> 3;
    int n_blk, m_blk, kc_ = 0;
    if constexpr (EPI == MEPI_PART) {
        // grid == 256: 64 m-blocks x 4 k-chunks; same-m chunks stay on one XCD
        m_blk = xcd * 8 + (s >> 2);
        kc_   = s & 3;
        n_blk = 0;
    } else {
        n_blk = s % nbn;
        m_blk = xcd * ((int)(gridDim.x >> 3) / nbn) + s / nbn;
    }
    const int m0 = m_blk * 128;
    const int n0 = n_blk * NW;

    const int tid  = threadIdx.x;
    const int lane = tid & 63;
    const int wv   = tid >> 6;
    const int wm   = (NW == 128) ? ((wv >> 1) << 6) : (wv << 5);
    const int wn   = (NW == 128) ? ((wv & 1) << 6) : 0;
    const int sr   = lane >> 2;
    const int scs  = (((lane & 3) ^ ((lane >> 4) & 3)) << 3);  // pre-swizzled source chunk
    const int quad = lane >> 4;
    const int c16  = lane & 15;

    f32x4 acc[MI][4] = {};
    const __hip_bfloat16* aptr = A + (size_t)(m0 + wv * 16 + sr) * lda + scs + kc_ * 256;
    const __hip_bfloat16* bptr = W + (size_t)(n0 + wv * 16 + sr) * K + scs;

#define STAGE(K0, BUF) { \
    __hip_bfloat16* asml = Asm[BUF] + wv * 16 * 32; \
    __hip_bfloat16* bsml = Bsm[BUF] + wv * 16 * 32; \
    __builtin_amdgcn_global_load_lds( \
        (const __attribute__((address_space(1))) void*)(aptr + (K0)), \
        (__attribute__((address_space(3))) void*)(asml), 16, 0, 0); \
    __builtin_amdgcn_global_load_lds( \
        (const __attribute__((address_space(1))) void*)(aptr + (size_t)64 * lda + (K0)), \
        (__attribute__((address_space(3))) void*)(asml + 64 * 32), 16, 0, 0); \
    __builtin_amdgcn_global_load_lds( \
        (const __attribute__((address_space(1))) void*)(bptr + (K0)), \
        (__attribute__((address_space(3))) void*)(bsml), 16, 0, 0); \
    if (NW == 128) \
        __builtin_amdgcn_global_load_lds( \
            (const __attribute__((address_space(1))) void*)(bptr + (size_t)64 * K + (K0)), \
            (__attribute__((address_space(3))) void*)(bsml + 64 * 32), 16, 0, 0); \
    }

    auto kstep = [&](int buf) {
        __builtin_amdgcn_s_barrier();            // A: cur-tile loads visible to all
        __builtin_amdgcn_sched_barrier(0);
        bf16x8 af[MI], bfr[4];
        const int csw = ((quad ^ ((c16 >> 2) & 3)) << 3);
        #pragma unroll
        for (int i = 0; i < MI; ++i)
            af[i]  = *(const bf16x8*)(Asm[buf] + (wm + i * 16 + c16) * 32 + csw);
        #pragma unroll
        for (int j = 0; j < 4; ++j)
            bfr[j] = *(const bf16x8*)(Bsm[buf] + (wn + j * 16 + c16) * 32 + csw);
        #pragma unroll
        for (int i = 0; i < MI; ++i)
            #pragma unroll
            for (int j = 0; j < 4; ++j)
                acc[i][j] = __builtin_amdgcn_mfma_f32_16x16x32_bf16(af[i], bfr[j], acc[i][j], 0, 0, 0);
        __builtin_amdgcn_sched_barrier(0);
        __builtin_amdgcn_s_barrier();            // B: all reads done -> buffer reusable
    };

    const int NT = K >> 5;                        // all call sites have NT >= 8
    STAGE(0, 0) STAGE(32, 1) STAGE(64, 2)
    int it = 0;
    for (; it + 3 < NT; ++it) {
        STAGE((it + 3) << 5, (it + 3) & 3)
        if constexpr (NW == 128) asm volatile("s_waitcnt vmcnt(12)" ::: "memory");
        else                     asm volatile("s_waitcnt vmcnt(9)"  ::: "memory");
        kstep(it & 3);
    }
    if constexpr (NW == 128) asm volatile("s_waitcnt vmcnt(8)" ::: "memory");
    else                     asm volatile("s_waitcnt vmcnt(6)" ::: "memory");
    kstep(it & 3); ++it;
    if constexpr (NW == 128) asm volatile("s_waitcnt vmcnt(4)" ::: "memory");
    else                     asm volatile("s_waitcnt vmcnt(3)" ::: "memory");
    kstep(it & 3); ++it;
    asm volatile("s_waitcnt vmcnt(0)" ::: "memory");
    kstep(it & 3);
#undef STAGE

    #pragma unroll
    for (int i = 0; i < MI; ++i) {
        const int mbase = m0 + wm + i * 16 + quad * 4;
        #pragma unroll
        for (int j = 0; j < 4; ++j) {
            const int n = n0 + wn + j * 16 + c16;
            if (n < N) {
                #pragma unroll
                for (int r = 0; r < 4; ++r) {
                    const size_t m = mbase + r;
                    float v = acc[i][j][r];
                    if (EPI == MEPI_TOK) {
                        v += bias[n] + pos[(m & (HIST - 1)) * DMODEL + coff + n];
                        Cb[m * ldcb + coff + n] = __float2bfloat16(v);
                    } else if (EPI == MEPI_BF16) {
                        Cb[m * ldcb + n] = __float2bfloat16(v);
                    } else if (EPI == MEPI_SPLIT) {
                        if (n < DTRANK) Cf[m * 32 + n] = v;
                        else Cb[(m >> 1) * 64 + (n & 15) * 4 + (m & 1) * 2 + ((n >> 4) & 1)]
                                 = __float2bfloat16(v);
                    } else if (EPI == MEPI_PART) {
                        Cf[((size_t)kc_ * MROWS + m) * 64 + n] = v;
                    } else { // MEPI_RELUB
                        Cb[m * ldcb + n] = __float2bfloat16(fmaxf(v + bias[n], 0.f));
                    }
                }
            }
        }
    }
}

// sums the 4 split-K partials; n<32 -> xdt (f32), n>=32 -> bcb (packed bf16)
__global__ __launch_bounds__(256)
void combine_split_kernel(const float* __restrict__ p, float* __restrict__ xdt,
                          __hip_bfloat16* __restrict__ bcb)
{
    const int idx = blockIdx.x * 256 + threadIdx.x;     // MROWS*16
    const int m  = idx >> 4;
    const int n4 = (idx & 15) << 2;
    const float4 a = *(const float4*)(p + (size_t)m * 64 + n4);
    const float4 b = *(const float4*)(p + ((size_t)MROWS + m) * 64 + n4);
    const float4 c = *(const float4*)(p + ((size_t)2 * MROWS + m) * 64 + n4);
    const float4 d = *(const float4*)(p + ((size_t)3 * MROWS + m) * 64 + n4);
    const float v[4] = { a.x + b.x + c.x + d.x, a.y + b.y + c.y + d.y,
                         a.z + b.z + c.z + d.z, a.w + b.w + c.w + d.w };
    if (n4 < 32) {
        *(float4*)(xdt + (size_t)m * 32 + n4) = make_float4(v[0], v[1], v[2], v[3]);
    } else {
        #pragma unroll
        for (int j = 0; j < 4; ++j) {
            const int n = n4 + j;
            bcb[(m >> 1) * 64 + (n & 15) * 4 + (m & 1) * 2 + ((n >> 4) & 1)]
                = __float2bfloat16(v[j]);
        }
    }
}

// ---------------------------------------------------------------------------
// f32 GEMM for W_dt (K=32): dtb = bf16(softplus(xdt @ W_dt^T + b_dt))
__global__ __launch_bounds__(256)
void gemm_f32_sp(const float* __restrict__ A, int lda,
                 const float* __restrict__ W,
                 __hip_bfloat16* __restrict__ C, int ldc,
                 int N, int K, const float* __restrict__ bias)
{
    __shared__ float As[32][68];
    __shared__ float Ws[32][68];
    const int tid = threadIdx.x;
    const int tx = tid & 15, ty = tid >> 4;
    const int m0 = blockIdx.y * 64;
    const int n0 = blockIdx.x * 64;
    const int lr = tid >> 3;
    const int lc = (tid & 7) << 2;
    float acc[4][4] = {};
    for (int k0 = 0; k0 < K; k0 += 32) {
        const float4 a0 = *(const float4*)(A + (size_t)(m0 + lr) * lda + k0 + lc);
        const float4 a1 = *(const float4*)(A + (size_t)(m0 + lr + 32) * lda + k0 + lc);
        const float4 b0 = *(const float4*)(W + (size_t)(n0 + lr) * K + k0 + lc);
        const float4 b1 = *(const float4*)(W + (size_t)(n0 + lr + 32) * K + k0 + lc);
        __syncthreads();
        As[lc+0][lr] = a0.x; As[lc+1][lr] = a0.y; As[lc+2][lr] = a0.z; As[lc+3][lr] = a0.w;
        As[lc+0][lr+32] = a1.x; As[lc+1][lr+32] = a1.y; As[lc+2][lr+32] = a1.z; As[lc+3][lr+32] = a1.w;
        Ws[lc+0][lr] = b0.x; Ws[lc+1][lr] = b0.y; Ws[lc+2][lr] = b0.z; Ws[lc+3][lr] = b0.w;
        Ws[lc+0][lr+32] = b1.x; Ws[lc+1][lr+32] = b1.y; Ws[lc+2][lr+32] = b1.z; Ws[lc+3][lr+32] = b1.w;
        __syncthreads();
        #pragma unroll
        for (int k = 0; k < 32; ++k) {
            const float4 a4 = *(const float4*)&As[k][ty << 2];
            const float4 b4 = *(const float4*)&Ws[k][tx << 2];
            const float a[4] = {a4.x, a4.y, a4.z, a4.w};
            const float b[4] = {b4.x, b4.y, b4.z, b4.w};
            #pragma unroll
            for (int i = 0; i < 4; ++i)
                #pragma unroll
                for (int j = 0; j < 4; ++j)
                    acc[i][j] = fmaf(a[i], b[j], acc[i][j]);
        }
    }
    const int mb = m0 + (ty << 2);
    const int nb = n0 + (tx << 2);
    #pragma unroll
    for (int i = 0; i < 4; ++i) {
        const size_t m = mb + i;
        #pragma unroll
        for (int j = 0; j < 4; ++j) {
            const int n = nb + j;
            C[m * ldc + n] = __float2bfloat16(softplusf(acc[i][j] + bias[n]));
        }
    }
}

// ---------------------------------------------------------------------------
__global__ __launch_bounds__(256)
void cast_bf16_kernel(const float* __restrict__ src, __hip_bfloat16* __restrict__ dst, int n4)
{
    const int i = blockIdx.x * 256 + threadIdx.x;
    if (i >= n4) return;
    const float4 v = ((const float4*)src)[i];
    union { __hip_bfloat16 h[4]; short4 s; } o;
    o.h[0] = __float2bfloat16(v.x); o.h[1] = __float2bfloat16(v.y);
    o.h[2] = __float2bfloat16(v.z); o.h[3] = __float2bfloat16(v.w);
    ((short4*)dst)[i] = o.s;
}

__global__ __launch_bounds__(256)
void cast_pad_kernel(const float* __restrict__ src, __hip_bfloat16* __restrict__ dst,
                     int nrows, int K4, int total4)
{
    const int i = blockIdx.x * 256 + threadIdx.x;
    if (i >= total4) return;
    const int row = i / K4;
    float4 v = make_float4(0.f, 0.f, 0.f, 0.f);
    if (row < nrows) v = ((const float4*)src)[i];
    union { __hip_bfloat16 h[4]; short4 s; } o;
    o.h[0] = __float2bfloat16(v.x); o.h[1] = __float2bfloat16(v.y);
    o.h[2] = __float2bfloat16(v.z); o.h[3] = __float2bfloat16(v.w);
    ((short4*)dst)[i] = o.s;
}

__global__ __launch_bounds__(256)
void embed_kernel(const int* __restrict__ actions, const float* __restrict__ act_emb,
                  const float* __restrict__ pos_emb, __hip_bfloat16* __restrict__ xb)
{
    const int idx = blockIdx.x * 256 + threadIdx.x;   // MROWS*64
    const int e = idx & 63;
    const int m = idx >> 6;
    const int l = m & (HIST - 1);
    const int b = m >> 8;
    float v = pos_emb[l * DMODEL + e];
    if (l > 0) {
        const int a = actions[b * HIST + l - 1];
        v += act_emb[a * ADIM + e];
    }
    xb[(size_t)m * DMODEL + e] = __float2bfloat16(v);
}

// xcb[m,d] = bf16(silu(conv_b[d] + sum_k conv_w[d,k]*xi[l-3+k, d]))
__global__ __launch_bounds__(256)
void conv_silu_kernel(const __hip_bfloat16* __restrict__ xzb, const float* __restrict__ cw,
                      const float* __restrict__ cb, __hip_bfloat16* __restrict__ xcb)
{
    const int idx = blockIdx.x * 256 + threadIdx.x;   // MROWS*DINNER
    const int d = idx & (DINNER - 1);
    const int m = idx >> 10;
    const int l = m & (HIST - 1);
    const float4 w = ((const float4*)cw)[d];
    const __hip_bfloat16* basep = xzb + (size_t)m * (2 * DINNER) + d;
    float acc = cb[d] + w.w * __bfloat162float(basep[0]);
    if (l >= 1) acc = fmaf(w.z, __bfloat162float(basep[-2 * DINNER]), acc);
    if (l >= 2) acc = fmaf(w.y, __bfloat162float(basep[-4 * DINNER]), acc);
    if (l >= 3) acc = fmaf(w.x, __bfloat162float(basep[-6 * DINNER]), acc);
    xcb[idx] = __float2bfloat16(siluf(acc));
}

// ---------------------------------------------------------------------------
// Selective scan v5: chunked double-buffered staging, transposed LDS,
// z register prefetch, XCD swizzle, exp2-folded A, fused single-instruction
// DPP butterfly adds (v_add_f32_dpp).
#define DPPA(x, CTRL) { float _t; \
    asm("v_add_f32_dpp %0, %1, %1 " CTRL " row_mask:0xf bank_mask:0xf" \
        : "=v"(_t) : "v"(x)); x = _t; }

__global__ __launch_bounds__(256)
void scan_kernel(const __hip_bfloat16* __restrict__ dtb, const __hip_bfloat16* __restrict__ bcb,
                 const __hip_bfloat16* __restrict__ xcb, const __hip_bfloat16* __restrict__ zb,
                 const float* __restrict__ A_log, const float* __restrict__ D_p,
                 __hip_bfloat16* __restrict__ yb)
{
    // [buf][channel 16][step 64 + pad4] u32 {dt lo16, xc hi16} / {B lo16, C hi16}
    __shared__ unsigned sdx[2][16][68];
    __shared__ unsigned sbc[2][16][68];

    const int tid = threadIdx.x;
    const int n   = tid & 15;     // state
    const int g   = tid >> 4;     // channel within block

    const int bid = blockIdx.x;
    const int blk = ((bid & 7) << 8) | (bid >> 3);
    const int c0  = blk * 16;
    const int b   = c0 >> 10;
    const int d0  = c0 & (DINNER - 1);
    const int d   = d0 + g;
    const size_t row0 = (size_t)b * HIST;

    const int sr = tid >> 2;
    const int sq = tid & 3;
    const unsigned short* dtu = (const unsigned short*)dtb;
    const unsigned short* xcu = (const unsigned short*)xcb;
    const unsigned short* zu  = (const unsigned short*)zb;
    const unsigned*       bcu = (const unsigned*)bcb;

    const float Ar = -__expf(A_log[d * DSTATE + n]);
#if __has_builtin(__builtin_amdgcn_exp2f)
    const float A2 = Ar * 1.44269504089f;
#define DAEXP(x) __builtin_amdgcn_exp2f((x) * A2)
#else
#define DAEXP(x) __expf((x) * Ar)
#endif
    const float Dp = D_p[d];
    float h = 0.f;

    uint2 dv, xv; uint4 bv;
    unsigned short za[4], znx[4];

#define SLOAD(cc) { \
    const size_t rb = (row0 + (size_t)(cc) * 64 + sr) * DINNER + d0 + sq * 4; \
    dv = *(const uint2*)(dtu + rb); \
    xv = *(const uint2*)(xcu + rb); \
    bv = *(const uint4*)(bcu + row0 * 16 + (size_t)(cc) * 1024 + tid * 4); \
}
#define SWRITE(bb) { \
    const int ch = sq * 4; \
    sdx[bb][ch + 0][sr] = (dv.x & 0xffffu) | (xv.x << 16); \
    sdx[bb][ch + 1][sr] = (dv.x >> 16)     | (xv.x & 0xffff0000u); \
    sdx[bb][ch + 2][sr] = (dv.y & 0xffffu) | (xv.y << 16); \
    sdx[bb][ch + 3][sr] = (dv.y >> 16)     | (xv.y & 0xffff0000u); \
    const int e2 = (tid & 7) * 2, p2 = (tid >> 3) * 2; \
    sbc[bb][e2 + 0][p2 + 0] = bv.x; \
    sbc[bb][e2 + 0][p2 + 1] = bv.y; \
    sbc[bb][e2 + 1][p2 + 0] = bv.z; \
    sbc[bb][e2 + 1][p2 + 1] = bv.w; \
}
#define ZLOAD(cc, arr) { \
    _Pragma("unroll") \
    for (int w = 0; w < 4; ++w) \
        arr[w] = zu[(row0 + (size_t)(cc) * 64 + w * 16 + n) * (2 * DINNER) + d0 + g]; \
}
#define SSTEP(Q, R, KK) { \
    const float dt = bflo(Q), xc = bfhi(Q); \
    const float Bv = bflo(R), Cv = bfhi(R); \
    const float dA = DAEXP(dt); \
    h = fmaf(dA, h, dt * xc * Bv); \
    float ctr = h * Cv; \
    DPPA(ctr, "quad_perm:[1,0,3,2]") \
    DPPA(ctr, "quad_perm:[2,3,0,1]") \
    DPPA(ctr, "row_half_mirror") \
    DPPA(ctr, "row_mirror") \
    if (n == (KK)) yreg = ctr; \
}

    SLOAD(0)
    ZLOAD(0, za)
    SWRITE(0)
    __syncthreads();

    for (int c = 0; c < 4; ++c) {
        const int buf = c & 1;
        if (c < 3) { SLOAD(c + 1) ZLOAD(c + 1, znx) }   // issue early (T14)

        const unsigned (*sdxc)[68] = sdx[buf];
        const unsigned (*sbcc)[68] = sbc[buf];
        #pragma unroll
        for (int w = 0; w < 4; ++w) {
            float yreg = 0.f;
            #pragma unroll
            for (int jq = 0; jq < 4; ++jq) {
                const uint4 qv = *(const uint4*)&sdxc[g][w * 16 + jq * 4];
                const uint4 rv = *(const uint4*)&sbcc[n][w * 16 + jq * 4];
                SSTEP(qv.x, rv.x, jq * 4 + 0)
                SSTEP(qv.y, rv.y, jq * 4 + 1)
                SSTEP(qv.z, rv.z, jq * 4 + 2)
                SSTEP(qv.w, rv.w, jq * 4 + 3)
            }
            const float xcf = bfhi(sdxc[g][w * 16 + n]);
            const float ze  = __uint_as_float((unsigned)za[w] << 16);
            yb[(row0 + c * 64 + w * 16 + n) * DINNER + d] =
                __float2bfloat16((yreg + xcf * Dp) * siluf(ze));
        }

        if (c < 3) SWRITE((c + 1) & 1)   // write late, after compute covered latency
        __syncthreads();
        #pragma unroll
        for (int w = 0; w < 4; ++w) za[w] = znx[w];
    }
#undef SLOAD
#undef SWRITE
#undef ZLOAD
#undef SSTEP
#undef DAEXP
}

// out[m,n] = b2[n] + sum_k h[m,k]*W2[n,k]  (h in bf16)
__global__ __launch_bounds__(256)
void ffn2_kernel(const __hip_bfloat16* __restrict__ h, const float* __restrict__ W2,
                 const float* __restrict__ b2, float* __restrict__ out)
{
    const int idx = blockIdx.x * 256 + threadIdx.x;   // MROWS*32
    const int n = idx & 31;
    const int m = idx >> 5;
    if (n >= 18) return;
    const unsigned short* hr = (const unsigned short*)(h + (size_t)m * DMODEL);
    const float* wr = W2 + (size_t)n * DMODEL;
    float acc = b2[n];
    for (int k = 0; k < DMODEL; k += 8) {
        const uint4 hv = *(const uint4*)(hr + k);
        const float4 w0 = *(const float4*)(wr + k);
        const float4 w1 = *(const float4*)(wr + k + 4);
        acc = fmaf(bflo(hv.x), w0.x, acc);
        acc = fmaf(bfhi(hv.x), w0.y, acc);
        acc = fmaf(bflo(hv.y), w0.z, acc);
        acc = fmaf(bfhi(hv.y), w0.w, acc);
        acc = fmaf(bflo(hv.z), w1.x, acc);
        acc = fmaf(bfhi(hv.z), w1.y, acc);
        acc = fmaf(bflo(hv.w), w1.z, acc);
        acc = fmaf(bfhi(hv.w), w1.w, acc);
    }
    out[(size_t)m * 18 + n] = acc;
}

extern "C" void kernel_launch(void* const* d_in, const int* in_sizes, int n_in,
                              void* d_out, int out_size, void* d_ws, size_t ws_size,
                              hipStream_t stream)
{
    const float* obss    = (const float*)d_in[0];
    const int*   actions = (const int*)  d_in[1];
    const float* obs_W   = (const float*)d_in[2];
    const float* obs_b   = (const float*)d_in[3];
    const float* act_emb = (const float*)d_in[4];
    const float* pos_emb = (const float*)d_in[5];
    const float* W_in    = (const float*)d_in[6];
    const float* conv_w  = (const float*)d_in[7];
    const float* conv_b  = (const float*)d_in[8];
    const float* W_x     = (const float*)d_in[9];
    const float* W_dt    = (const float*)d_in[10];
    const float* b_dt    = (const float*)d_in[11];
    const float* A_log   = (const float*)d_in[12];
    const float* D_p     = (const float*)d_in[13];
    const float* W_out   = (const float*)d_in[14];
    const float* ffn_W1  = (const float*)d_in[15];
    const float* ffn_b1  = (const float*)d_in[16];
    const float* ffn_W2  = (const float*)d_in[17];
    const float* ffn_b2  = (const float*)d_in[18];
    float* out = (float*)d_out;

    const size_t MiB = 1024 * 1024;
    char* base = (char*)d_ws;
    __hip_bfloat16* xb    = (__hip_bfloat16*)(base);
    __hip_bfloat16* xzb   = (__hip_bfloat16*)(base + 8 * MiB);
    __hip_bfloat16* xcb   = (__hip_bfloat16*)(base + 40 * MiB);
    __hip_bfloat16* dtb   = (__hip_bfloat16*)(base + 56 * MiB);
    __hip_bfloat16* yb    = (__hip_bfloat16*)(base + 88 * MiB);
    float*          xdt   = (float*)(base + 104 * MiB);
    __hip_bfloat16* bcb   = (__hip_bfloat16*)(base + 105 * MiB);
    __hip_bfloat16* wbuf  = (__hip_bfloat16*)(base + 106 * MiB);
    __hip_bfloat16* wxb   = (__hip_bfloat16*)(base + 110 * MiB);
    float*          xdtp  = (float*)(base + 112 * MiB);          // 4 x 2 MiB split-K partials
    __hip_bfloat16* obssb = (__hip_bfloat16*)(base + 8 * MiB);
    __hip_bfloat16* hbuf  = (__hip_bfloat16*)(base + 8 * MiB);

    // --- prologue ---
    cast_bf16_kernel<<<(MROWS * OBSDIM / 4) / 256, 256, 0, stream>>>(obss, obssb, MROWS * OBSDIM / 4);
    cast_pad_kernel<<<(512 * OBSDIM / 4) / 256, 256, 0, stream>>>(obs_W, wbuf, OBSOUT, OBSDIM / 4, 512 * OBSDIM / 4);
    embed_kernel<<<MROWS * ADIM / 256, 256, 0, stream>>>(actions, act_emb, pos_emb, xb);
    gemm_mfma<MEPI_TOK, 64><<<8 * (MROWS / 128), 256, 0, stream>>>(
        obssb, OBSDIM, wbuf, nullptr, 0, xb, DMODEL, ADIM, OBSOUT, OBSDIM, 8, obs_b, pos_emb);

    for (int i = 0; i < NLAYERS; ++i) {
        // W_in: xzb = bf16(xb @ W_in^T), ld 2048 (xi | z)
        cast_bf16_kernel<<<(2 * DINNER * DMODEL / 4) / 256, 256, 0, stream>>>(
            W_in + (size_t)i * 2 * DINNER * DMODEL, wbuf, 2 * DINNER * DMODEL / 4);
        gemm_mfma<MEPI_BF16, 128><<<(2 * DINNER / 128) * (MROWS / 128), 256, 0, stream>>>(
            xb, DMODEL, wbuf, nullptr, 0, xzb, 2 * DINNER, 0, 2 * DINNER, DMODEL,
            2 * DINNER / 128, nullptr, nullptr);
        conv_silu_kernel<<<MROWS * DINNER / 256, 256, 0, stream>>>(
            xzb, conv_w + (size_t)i * DINNER * 4, conv_b + (size_t)i * DINNER, xcb);
        // W_x: split-K=4 partials then combine into xdt (f32) + bcb (packed bf16)
        cast_pad_kernel<<<(128 * DINNER / 4) / 256, 256, 0, stream>>>(
            W_x + (size_t)i * 64 * DINNER, wxb, 64, DINNER / 4, 128 * DINNER / 4);
        gemm_mfma<MEPI_PART, 64><<<256, 256, 0, stream>>>(
            xcb, DINNER, wxb, xdtp, 0, nullptr, 0, 0, 64, 256, 1, nullptr, nullptr);
        combine_split_kernel<<<MROWS * 16 / 256, 256, 0, stream>>>(xdtp, xdt, bcb);
        // W_dt (f32, K=32, softplus): dtb (bf16)
        gemm_f32_sp<<<dim3(DINNER / 64, MROWS / 64), 256, 0, stream>>>(
            xdt, 32, W_dt + (size_t)i * DINNER * DTRANK, dtb, DINNER, DINNER, DTRANK,
            b_dt + (size_t)i * DINNER);
        scan_kernel<<<(32 * DINNER) / 16, 256, 0, stream>>>(
            dtb, bcb, xcb, xzb + DINNER, A_log + (size_t)i * DINNER * DSTATE,
            D_p + (size_t)i * DINNER, yb);
        // W_out: xb = bf16(yb @ W_out^T)
        cast_bf16_kernel<<<(DMODEL * DINNER / 4) / 256, 256, 0, stream>>>(
            W_out + (size_t)i * DMODEL * DINNER, wbuf, DMODEL * DINNER / 4);
        gemm_mfma<MEPI_BF16, 64><<<(DMODEL / 64) * (MROWS / 128), 256, 0, stream>>>(
            yb, DINNER, wbuf, nullptr, 0, xb, DMODEL, 0, DMODEL, DINNER,
            DMODEL / 64, nullptr, nullptr);
    }

    cast_bf16_kernel<<<(DMODEL * DMODEL / 4) / 256, 256, 0, stream>>>(ffn_W1, wbuf, DMODEL * DMODEL / 4);
    gemm_mfma<MEPI_RELUB, 64><<<(DMODEL / 64) * (MROWS / 128), 256, 0, stream>>>(
        xb, DMODEL, wbuf, nullptr, 0, hbuf, DMODEL, 0, DMODEL, DMODEL,
        DMODEL / 64, ffn_b1, nullptr);
    ffn2_kernel<<<MROWS * 32 / 256, 256, 0, stream>>>(hbuf, ffn_W2, ffn_b2, out);
}

// Round 5
// 1108.359 us; speedup vs baseline: 1.1575x; 1.0269x over previous
//
#include <hip/hip_runtime.h>
#include <hip/hip_bf16.h>
#include <cstdint>
#include <cstddef>

#define HIST    256
#define DMODEL  512
#define DINNER  1024
#define DSTATE  16
#define DTRANK  32
#define OBSDIM  4096
#define OBSOUT  448
#define ADIM    64
#define NLAYERS 4
#define MROWS   8192   // BATCH*HIST

typedef __bf16  bf16x8 __attribute__((ext_vector_type(8)));
typedef float   f32x4  __attribute__((ext_vector_type(4)));

enum { MEPI_TOK = 0, MEPI_BF16 = 1, MEPI_SPLIT = 2, MEPI_RELUB = 3, MEPI_PART = 4 };

__device__ __forceinline__ float siluf(float x) { return x / (1.f + __expf(-x)); }
__device__ __forceinline__ float softplusf(float x) {
    return fmaxf(x, 0.f) + log1pf(__expf(-fabsf(x)));
}
__device__ __forceinline__ float bflo(unsigned u) { return __uint_as_float(u << 16); }
__device__ __forceinline__ float bfhi(unsigned u) { return __uint_as_float(u & 0xffff0000u); }

// ---------------------------------------------------------------------------
// bf16 MFMA GEMM, 128xNW tile (NW = 128 or 64), BK=32, multi-buffer LDS.
// NW=64: 4 buffers, prefetch depth 3 (48 KB, 3 blocks/CU).
// NW=128: 3 buffers, prefetch depth 2 (48 KB, 3 blocks/CU) -- R4's 4-buffer
//   64 KB variant halved occupancy (2 blocks/CU) and was a wash; depth-2 at
//   3 blocks/CU keeps both ILP and TLP.
// Two raw barriers per K-step (proven structure): A = cur-tile loads visible;
// B = all reads of cur done before anyone's next STAGE overwrites it.
// Main loop waits vmcnt(depth*L); peeled tail drains stepwise to 0.
// MEPI_PART: split-K over 4 chunks of 256 for the W_x projection.
template<int EPI, int NW>
__global__ __launch_bounds__(256)
void gemm_mfma(const __hip_bfloat16* __restrict__ A, int lda,
               const __hip_bfloat16* __restrict__ W,
               float* __restrict__ Cf, int ldc,
               __hip_bfloat16* __restrict__ Cb, int ldcb,
               int coff, int N, int K, int nbn,
               const float* __restrict__ bias, const float* __restrict__ pos)
{
    constexpr int MI   = (NW == 128) ? 4 : 2;   // 16-row fragments per wave (M dir)
    constexpr int NBUF = (NW == 128) ? 3 : 4;
    __shared__ __hip_bfloat16 Asm[NBUF][128 * 32];
    __shared__ __hip_bfloat16 Bsm[NBUF][NW * 32];
    const int bid = blockIdx.x;
    const int xcd = bid & 7;
    const int s   = bid >> 3;
    int n_blk, m_blk, kc_ = 0;
    if constexpr (EPI == MEPI_PART) {
        // grid == 256: 64 m-blocks x 4 k-chunks; same-m chunks stay on one XCD
        m_blk = xcd * 8 + (s >> 2);
        kc_   = s & 3;
        n_blk = 0;
    } else {
        n_blk = s % nbn;
        m_blk = xcd * ((int)(gridDim.x >> 3) / nbn) + s / nbn;
    }
    const int m0 = m_blk * 128;
    const int n0 = n_blk * NW;

    const int tid  = threadIdx.x;
    const int lane = tid & 63;
    const int wv   = tid >> 6;
    const int wm   = (NW == 128) ? ((wv >> 1) << 6) : (wv << 5);
    const int wn   = (NW == 128) ? ((wv & 1) << 6) : 0;
    const int sr   = lane >> 2;
    const int scs  = (((lane & 3) ^ ((lane >> 4) & 3)) << 3);  // pre-swizzled source chunk
    const int quad = lane >> 4;
    const int c16  = lane & 15;

    f32x4 acc[MI][4] = {};
    const __hip_bfloat16* aptr = A + (size_t)(m0 + wv * 16 + sr) * lda + scs + kc_ * 256;
    const __hip_bfloat16* bptr = W + (size_t)(n0 + wv * 16 + sr) * K + scs;

#define STAGE(K0, BUF) { \
    __hip_bfloat16* asml = Asm[BUF] + wv * 16 * 32; \
    __hip_bfloat16* bsml = Bsm[BUF] + wv * 16 * 32; \
    __builtin_amdgcn_global_load_lds( \
        (const __attribute__((address_space(1))) void*)(aptr + (K0)), \
        (__attribute__((address_space(3))) void*)(asml), 16, 0, 0); \
    __builtin_amdgcn_global_load_lds( \
        (const __attribute__((address_space(1))) void*)(aptr + (size_t)64 * lda + (K0)), \
        (__attribute__((address_space(3))) void*)(asml + 64 * 32), 16, 0, 0); \
    __builtin_amdgcn_global_load_lds( \
        (const __attribute__((address_space(1))) void*)(bptr + (K0)), \
        (__attribute__((address_space(3))) void*)(bsml), 16, 0, 0); \
    if (NW == 128) \
        __builtin_amdgcn_global_load_lds( \
            (const __attribute__((address_space(1))) void*)(bptr + (size_t)64 * K + (K0)), \
            (__attribute__((address_space(3))) void*)(bsml + 64 * 32), 16, 0, 0); \
    }

    auto kstep = [&](int buf) {
        __builtin_amdgcn_s_barrier();            // A: cur-tile loads visible to all
        __builtin_amdgcn_sched_barrier(0);
        bf16x8 af[MI], bfr[4];
        const int csw = ((quad ^ ((c16 >> 2) & 3)) << 3);
        #pragma unroll
        for (int i = 0; i < MI; ++i)
            af[i]  = *(const bf16x8*)(Asm[buf] + (wm + i * 16 + c16) * 32 + csw);
        #pragma unroll
        for (int j = 0; j < 4; ++j)
            bfr[j] = *(const bf16x8*)(Bsm[buf] + (wn + j * 16 + c16) * 32 + csw);
        #pragma unroll
        for (int i = 0; i < MI; ++i)
            #pragma unroll
            for (int j = 0; j < 4; ++j)
                acc[i][j] = __builtin_amdgcn_mfma_f32_16x16x32_bf16(af[i], bfr[j], acc[i][j], 0, 0, 0);
        __builtin_amdgcn_sched_barrier(0);
        __builtin_amdgcn_s_barrier();            // B: all reads done -> buffer reusable
    };

    const int NT = K >> 5;                        // all call sites have NT >= NBUF
    #pragma unroll
    for (int t = 0; t < NBUF - 1; ++t) STAGE(t << 5, t)
    int sb = NBUF - 1, cb = 0;
    int it = 0;
    for (; it + NBUF - 1 < NT; ++it) {
        STAGE((it + NBUF - 1) << 5, sb)
        sb = (sb + 1 == NBUF) ? 0 : sb + 1;
        if constexpr (NW == 128) asm volatile("s_waitcnt vmcnt(8)" ::: "memory");
        else                     asm volatile("s_waitcnt vmcnt(9)" ::: "memory");
        kstep(cb);
        cb = (cb + 1 == NBUF) ? 0 : cb + 1;
    }
    if constexpr (NW == 64) {   // depth-3 tail: 6, 3, 0
        asm volatile("s_waitcnt vmcnt(6)" ::: "memory");
        kstep(cb); cb = (cb + 1 == NBUF) ? 0 : cb + 1;
        asm volatile("s_waitcnt vmcnt(3)" ::: "memory");
        kstep(cb); cb = (cb + 1 == NBUF) ? 0 : cb + 1;
        asm volatile("s_waitcnt vmcnt(0)" ::: "memory");
        kstep(cb);
    } else {                    // depth-2 tail: 4, 0
        asm volatile("s_waitcnt vmcnt(4)" ::: "memory");
        kstep(cb); cb = (cb + 1 == NBUF) ? 0 : cb + 1;
        asm volatile("s_waitcnt vmcnt(0)" ::: "memory");
        kstep(cb);
    }
#undef STAGE

    #pragma unroll
    for (int i = 0; i < MI; ++i) {
        const int mbase = m0 + wm + i * 16 + quad * 4;
        #pragma unroll
        for (int j = 0; j < 4; ++j) {
            const int n = n0 + wn + j * 16 + c16;
            if (n < N) {
                #pragma unroll
                for (int r = 0; r < 4; ++r) {
                    const size_t m = mbase + r;
                    float v = acc[i][j][r];
                    if (EPI == MEPI_TOK) {
                        v += bias[n] + pos[(m & (HIST - 1)) * DMODEL + coff + n];
                        Cb[m * ldcb + coff + n] = __float2bfloat16(v);
                    } else if (EPI == MEPI_BF16) {
                        Cb[m * ldcb + n] = __float2bfloat16(v);
                    } else if (EPI == MEPI_SPLIT) {
                        if (n < DTRANK) Cf[m * 32 + n] = v;
                        else Cb[(m >> 1) * 64 + (n & 15) * 4 + (m & 1) * 2 + ((n >> 4) & 1)]
                                 = __float2bfloat16(v);
                    } else if (EPI == MEPI_PART) {
                        Cf[((size_t)kc_ * MROWS + m) * 64 + n] = v;
                    } else { // MEPI_RELUB
                        Cb[m * ldcb + n] = __float2bfloat16(fmaxf(v + bias[n], 0.f));
                    }
                }
            }
        }
    }
}

// sums the 4 split-K partials; n<32 -> xdt (f32), n>=32 -> bcb (packed bf16)
__global__ __launch_bounds__(256)
void combine_split_kernel(const float* __restrict__ p, float* __restrict__ xdt,
                          __hip_bfloat16* __restrict__ bcb)
{
    const int idx = blockIdx.x * 256 + threadIdx.x;     // MROWS*16
    const int m  = idx >> 4;
    const int n4 = (idx & 15) << 2;
    const float4 a = *(const float4*)(p + (size_t)m * 64 + n4);
    const float4 b = *(const float4*)(p + ((size_t)MROWS + m) * 64 + n4);
    const float4 c = *(const float4*)(p + ((size_t)2 * MROWS + m) * 64 + n4);
    const float4 d = *(const float4*)(p + ((size_t)3 * MROWS + m) * 64 + n4);
    const float v[4] = { a.x + b.x + c.x + d.x, a.y + b.y + c.y + d.y,
                         a.z + b.z + c.z + d.z, a.w + b.w + c.w + d.w };
    if (n4 < 32) {
        *(float4*)(xdt + (size_t)m * 32 + n4) = make_float4(v[0], v[1], v[2], v[3]);
    } else {
        #pragma unroll
        for (int j = 0; j < 4; ++j) {
            const int n = n4 + j;
            bcb[(m >> 1) * 64 + (n & 15) * 4 + (m & 1) * 2 + ((n >> 4) & 1)]
                = __float2bfloat16(v[j]);
        }
    }
}

// ---------------------------------------------------------------------------
// f32 GEMM for W_dt (K=32): dtb = bf16(softplus(xdt @ W_dt^T + b_dt))
__global__ __launch_bounds__(256)
void gemm_f32_sp(const float* __restrict__ A, int lda,
                 const float* __restrict__ W,
                 __hip_bfloat16* __restrict__ C, int ldc,
                 int N, int K, const float* __restrict__ bias)
{
    __shared__ float As[32][68];
    __shared__ float Ws[32][68];
    const int tid = threadIdx.x;
    const int tx = tid & 15, ty = tid >> 4;
    const int m0 = blockIdx.y * 64;
    const int n0 = blockIdx.x * 64;
    const int lr = tid >> 3;
    const int lc = (tid & 7) << 2;
    float acc[4][4] = {};
    for (int k0 = 0; k0 < K; k0 += 32) {
        const float4 a0 = *(const float4*)(A + (size_t)(m0 + lr) * lda + k0 + lc);
        const float4 a1 = *(const float4*)(A + (size_t)(m0 + lr + 32) * lda + k0 + lc);
        const float4 b0 = *(const float4*)(W + (size_t)(n0 + lr) * K + k0 + lc);
        const float4 b1 = *(const float4*)(W + (size_t)(n0 + lr + 32) * K + k0 + lc);
        __syncthreads();
        As[lc+0][lr] = a0.x; As[lc+1][lr] = a0.y; As[lc+2][lr] = a0.z; As[lc+3][lr] = a0.w;
        As[lc+0][lr+32] = a1.x; As[lc+1][lr+32] = a1.y; As[lc+2][lr+32] = a1.z; As[lc+3][lr+32] = a1.w;
        Ws[lc+0][lr] = b0.x; Ws[lc+1][lr] = b0.y; Ws[lc+2][lr] = b0.z; Ws[lc+3][lr] = b0.w;
        Ws[lc+0][lr+32] = b1.x; Ws[lc+1][lr+32] = b1.y; Ws[lc+2][lr+32] = b1.z; Ws[lc+3][lr+32] = b1.w;
        __syncthreads();
        #pragma unroll
        for (int k = 0; k < 32; ++k) {
            const float4 a4 = *(const float4*)&As[k][ty << 2];
            const float4 b4 = *(const float4*)&Ws[k][tx << 2];
            const float a[4] = {a4.x, a4.y, a4.z, a4.w};
            const float b[4] = {b4.x, b4.y, b4.z, b4.w};
            #pragma unroll
            for (int i = 0; i < 4; ++i)
                #pragma unroll
                for (int j = 0; j < 4; ++j)
                    acc[i][j] = fmaf(a[i], b[j], acc[i][j]);
        }
    }
    const int mb = m0 + (ty << 2);
    const int nb = n0 + (tx << 2);
    #pragma unroll
    for (int i = 0; i < 4; ++i) {
        const size_t m = mb + i;
        #pragma unroll
        for (int j = 0; j < 4; ++j) {
            const int n = nb + j;
            C[m * ldc + n] = __float2bfloat16(softplusf(acc[i][j] + bias[n]));
        }
    }
}

// ---------------------------------------------------------------------------
// One consolidated cast kernel: all f32 -> bf16 weight/input staging in a
// single launch (replaces 15 small cast/cast_pad launches per iteration).
// Segment s covers blocks [blk_start[s], blk_start[s+1]); padded segments
// zero rows >= nrows (row = idx >> shift).
#define NSEG 15
struct CastSegs {
    const float* src[NSEG];
    unsigned long long dstoff[NSEG];   // byte offset into workspace
    int blk_start[NSEG + 1];
    int n4[NSEG];
    int shift[NSEG];
    int nrows[NSEG];
};

__global__ __launch_bounds__(256)
void cast_all_kernel(CastSegs cs, char* wsbase)
{
    const int blk = blockIdx.x;
    int s = 0;
    #pragma unroll 1
    while (s < NSEG - 1 && blk >= cs.blk_start[s + 1]) ++s;
    const int i = (blk - cs.blk_start[s]) * 256 + (int)threadIdx.x;
    if (i >= cs.n4[s]) return;
    const int row = i >> cs.shift[s];
    float4 v = make_float4(0.f, 0.f, 0.f, 0.f);
    if (row < cs.nrows[s]) v = ((const float4*)cs.src[s])[i];
    union { __hip_bfloat16 h[4]; short4 sh; } o;
    o.h[0] = __float2bfloat16(v.x); o.h[1] = __float2bfloat16(v.y);
    o.h[2] = __float2bfloat16(v.z); o.h[3] = __float2bfloat16(v.w);
    ((short4*)(wsbase + cs.dstoff[s]))[i] = o.sh;
}

__global__ __launch_bounds__(256)
void embed_kernel(const int* __restrict__ actions, const float* __restrict__ act_emb,
                  const float* __restrict__ pos_emb, __hip_bfloat16* __restrict__ xb)
{
    const int idx = blockIdx.x * 256 + threadIdx.x;   // MROWS*64
    const int e = idx & 63;
    const int m = idx >> 6;
    const int l = m & (HIST - 1);
    const int b = m >> 8;
    float v = pos_emb[l * DMODEL + e];
    if (l > 0) {
        const int a = actions[b * HIST + l - 1];
        v += act_emb[a * ADIM + e];
    }
    xb[(size_t)m * DMODEL + e] = __float2bfloat16(v);
}

// xcb[m,d] = bf16(silu(conv_b[d] + sum_k conv_w[d,k]*xi[l-3+k, d]))
__global__ __launch_bounds__(256)
void conv_silu_kernel(const __hip_bfloat16* __restrict__ xzb, const float* __restrict__ cw,
                      const float* __restrict__ cb, __hip_bfloat16* __restrict__ xcb)
{
    const int idx = blockIdx.x * 256 + threadIdx.x;   // MROWS*DINNER
    const int d = idx & (DINNER - 1);
    const int m = idx >> 10;
    const int l = m & (HIST - 1);
    const float4 w = ((const float4*)cw)[d];
    const __hip_bfloat16* basep = xzb + (size_t)m * (2 * DINNER) + d;
    float acc = cb[d] + w.w * __bfloat162float(basep[0]);
    if (l >= 1) acc = fmaf(w.z, __bfloat162float(basep[-2 * DINNER]), acc);
    if (l >= 2) acc = fmaf(w.y, __bfloat162float(basep[-4 * DINNER]), acc);
    if (l >= 3) acc = fmaf(w.x, __bfloat162float(basep[-6 * DINNER]), acc);
    xcb[idx] = __float2bfloat16(siluf(acc));
}

// ---------------------------------------------------------------------------
// Selective scan v5: chunked double-buffered staging, transposed LDS,
// z register prefetch, XCD swizzle, exp2-folded A, fused single-instruction
// DPP butterfly adds (v_add_f32_dpp).
#define DPPA(x, CTRL) { float _t; \
    asm("v_add_f32_dpp %0, %1, %1 " CTRL " row_mask:0xf bank_mask:0xf" \
        : "=v"(_t) : "v"(x)); x = _t; }

__global__ __launch_bounds__(256)
void scan_kernel(const __hip_bfloat16* __restrict__ dtb, const __hip_bfloat16* __restrict__ bcb,
                 const __hip_bfloat16* __restrict__ xcb, const __hip_bfloat16* __restrict__ zb,
                 const float* __restrict__ A_log, const float* __restrict__ D_p,
                 __hip_bfloat16* __restrict__ yb)
{
    // [buf][channel 16][step 64 + pad4] u32 {dt lo16, xc hi16} / {B lo16, C hi16}
    __shared__ unsigned sdx[2][16][68];
    __shared__ unsigned sbc[2][16][68];

    const int tid = threadIdx.x;
    const int n   = tid & 15;     // state
    const int g   = tid >> 4;     // channel within block

    const int bid = blockIdx.x;
    const int blk = ((bid & 7) << 8) | (bid >> 3);
    const int c0  = blk * 16;
    const int b   = c0 >> 10;
    const int d0  = c0 & (DINNER - 1);
    const int d   = d0 + g;
    const size_t row0 = (size_t)b * HIST;

    const int sr = tid >> 2;
    const int sq = tid & 3;
    const unsigned short* dtu = (const unsigned short*)dtb;
    const unsigned short* xcu = (const unsigned short*)xcb;
    const unsigned short* zu  = (const unsigned short*)zb;
    const unsigned*       bcu = (const unsigned*)bcb;

    const float Ar = -__expf(A_log[d * DSTATE + n]);
#if __has_builtin(__builtin_amdgcn_exp2f)
    const float A2 = Ar * 1.44269504089f;
#define DAEXP(x) __builtin_amdgcn_exp2f((x) * A2)
#else
#define DAEXP(x) __expf((x) * Ar)
#endif
    const float Dp = D_p[d];
    float h = 0.f;

    uint2 dv, xv; uint4 bv;
    unsigned short za[4], znx[4];

#define SLOAD(cc) { \
    const size_t rb = (row0 + (size_t)(cc) * 64 + sr) * DINNER + d0 + sq * 4; \
    dv = *(const uint2*)(dtu + rb); \
    xv = *(const uint2*)(xcu + rb); \
    bv = *(const uint4*)(bcu + row0 * 16 + (size_t)(cc) * 1024 + tid * 4); \
}
#define SWRITE(bb) { \
    const int ch = sq * 4; \
    sdx[bb][ch + 0][sr] = (dv.x & 0xffffu) | (xv.x << 16); \
    sdx[bb][ch + 1][sr] = (dv.x >> 16)     | (xv.x & 0xffff0000u); \
    sdx[bb][ch + 2][sr] = (dv.y & 0xffffu) | (xv.y << 16); \
    sdx[bb][ch + 3][sr] = (dv.y >> 16)     | (xv.y & 0xffff0000u); \
    const int e2 = (tid & 7) * 2, p2 = (tid >> 3) * 2; \
    sbc[bb][e2 + 0][p2 + 0] = bv.x; \
    sbc[bb][e2 + 0][p2 + 1] = bv.y; \
    sbc[bb][e2 + 1][p2 + 0] = bv.z; \
    sbc[bb][e2 + 1][p2 + 1] = bv.w; \
}
#define ZLOAD(cc, arr) { \
    _Pragma("unroll") \
    for (int w = 0; w < 4; ++w) \
        arr[w] = zu[(row0 + (size_t)(cc) * 64 + w * 16 + n) * (2 * DINNER) + d0 + g]; \
}
#define SSTEP(Q, R, KK) { \
    const float dt = bflo(Q), xc = bfhi(Q); \
    const float Bv = bflo(R), Cv = bfhi(R); \
    const float dA = DAEXP(dt); \
    h = fmaf(dA, h, dt * xc * Bv); \
    float ctr = h * Cv; \
    DPPA(ctr, "quad_perm:[1,0,3,2]") \
    DPPA(ctr, "quad_perm:[2,3,0,1]") \
    DPPA(ctr, "row_half_mirror") \
    DPPA(ctr, "row_mirror") \
    if (n == (KK)) yreg = ctr; \
}

    SLOAD(0)
    ZLOAD(0, za)
    SWRITE(0)
    __syncthreads();

    for (int c = 0; c < 4; ++c) {
        const int buf = c & 1;
        if (c < 3) { SLOAD(c + 1) ZLOAD(c + 1, znx) }   // issue early (T14)

        const unsigned (*sdxc)[68] = sdx[buf];
        const unsigned (*sbcc)[68] = sbc[buf];
        #pragma unroll
        for (int w = 0; w < 4; ++w) {
            float yreg = 0.f;
            #pragma unroll
            for (int jq = 0; jq < 4; ++jq) {
                const uint4 qv = *(const uint4*)&sdxc[g][w * 16 + jq * 4];
                const uint4 rv = *(const uint4*)&sbcc[n][w * 16 + jq * 4];
                SSTEP(qv.x, rv.x, jq * 4 + 0)
                SSTEP(qv.y, rv.y, jq * 4 + 1)
                SSTEP(qv.z, rv.z, jq * 4 + 2)
                SSTEP(qv.w, rv.w, jq * 4 + 3)
            }
            const float xcf = bfhi(sdxc[g][w * 16 + n]);
            const float ze  = __uint_as_float((unsigned)za[w] << 16);
            yb[(row0 + c * 64 + w * 16 + n) * DINNER + d] =
                __float2bfloat16((yreg + xcf * Dp) * siluf(ze));
        }

        if (c < 3) SWRITE((c + 1) & 1)   // write late, after compute covered latency
        __syncthreads();
        #pragma unroll
        for (int w = 0; w < 4; ++w) za[w] = znx[w];
    }
#undef SLOAD
#undef SWRITE
#undef ZLOAD
#undef SSTEP
#undef DAEXP
}

// out[m,n] = b2[n] + sum_k h[m,k]*W2[n,k]  (h in bf16)
__global__ __launch_bounds__(256)
void ffn2_kernel(const __hip_bfloat16* __restrict__ h, const float* __restrict__ W2,
                 const float* __restrict__ b2, float* __restrict__ out)
{
    const int idx = blockIdx.x * 256 + threadIdx.x;   // MROWS*32
    const int n = idx & 31;
    const int m = idx >> 5;
    if (n >= 18) return;
    const unsigned short* hr = (const unsigned short*)(h + (size_t)m * DMODEL);
    const float* wr = W2 + (size_t)n * DMODEL;
    float acc = b2[n];
    for (int k = 0; k < DMODEL; k += 8) {
        const uint4 hv = *(const uint4*)(hr + k);
        const float4 w0 = *(const float4*)(wr + k);
        const float4 w1 = *(const float4*)(wr + k + 4);
        acc = fmaf(bflo(hv.x), w0.x, acc);
        acc = fmaf(bfhi(hv.x), w0.y, acc);
        acc = fmaf(bflo(hv.y), w0.z, acc);
        acc = fmaf(bfhi(hv.y), w0.w, acc);
        acc = fmaf(bflo(hv.z), w1.x, acc);
        acc = fmaf(bfhi(hv.z), w1.y, acc);
        acc = fmaf(bflo(hv.w), w1.z, acc);
        acc = fmaf(bfhi(hv.w), w1.w, acc);
    }
    out[(size_t)m * 18 + n] = acc;
}

extern "C" void kernel_launch(void* const* d_in, const int* in_sizes, int n_in,
                              void* d_out, int out_size, void* d_ws, size_t ws_size,
                              hipStream_t stream)
{
    const float* obss    = (const float*)d_in[0];
    const int*   actions = (const int*)  d_in[1];
    const float* obs_W   = (const float*)d_in[2];
    const float* obs_b   = (const float*)d_in[3];
    const float* act_emb = (const float*)d_in[4];
    const float* pos_emb = (const float*)d_in[5];
    const float* W_in    = (const float*)d_in[6];
    const float* conv_w  = (const float*)d_in[7];
    const float* conv_b  = (const float*)d_in[8];
    const float* W_x     = (const float*)d_in[9];
    const float* W_dt    = (const float*)d_in[10];
    const float* b_dt    = (const float*)d_in[11];
    const float* A_log   = (const float*)d_in[12];
    const float* D_p     = (const float*)d_in[13];
    const float* W_out   = (const float*)d_in[14];
    const float* ffn_W1  = (const float*)d_in[15];
    const float* ffn_b1  = (const float*)d_in[16];
    const float* ffn_W2  = (const float*)d_in[17];
    const float* ffn_b2  = (const float*)d_in[18];
    float* out = (float*)d_out;

    const size_t MiB = 1024 * 1024;
    char* base = (char*)d_ws;
    __hip_bfloat16* xb    = (__hip_bfloat16*)(base);
    __hip_bfloat16* xzb   = (__hip_bfloat16*)(base + 8 * MiB);
    __hip_bfloat16* xcb   = (__hip_bfloat16*)(base + 40 * MiB);
    __hip_bfloat16* dtb   = (__hip_bfloat16*)(base + 56 * MiB);
    __hip_bfloat16* yb    = (__hip_bfloat16*)(base + 88 * MiB);
    float*          xdt   = (float*)(base + 104 * MiB);
    __hip_bfloat16* bcb   = (__hip_bfloat16*)(base + 105 * MiB);
    float*          xdtp  = (float*)(base + 112 * MiB);          // 4 x 2 MiB split-K partials
    __hip_bfloat16* obssb = (__hip_bfloat16*)(base + 8 * MiB);   // dead after TOK gemm
    __hip_bfloat16* hbuf  = (__hip_bfloat16*)(base + 8 * MiB);   // live only after last scan
    // persistent bf16 weight slots (cast once per iteration, all in one launch)
    const size_t WOBS_OFF = 128 * MiB;                           // 512x4096 (padded)
    const size_t WIN_OFF  = 132 * MiB;                           // 4 x 2 MiB
    const size_t WOUT_OFF = 140 * MiB;                           // 4 x 1 MiB
    const size_t WX_OFF   = 144 * MiB;                           // 4 x 0.25 MiB (padded)
    const size_t WF1_OFF  = 145 * MiB;                           // 0.5 MiB

    // --- one consolidated cast launch ---
    CastSegs cs{};
    int nb = 0, si = 0;
    auto addseg = [&](const float* src, size_t dstoff, int n4, int shift, int nrows) {
        cs.src[si] = src; cs.dstoff[si] = dstoff; cs.n4[si] = n4;
        cs.shift[si] = shift; cs.nrows[si] = nrows;
        cs.blk_start[si] = nb; nb += (n4 + 255) / 256; ++si;
    };
    addseg(obss, 8 * MiB, MROWS * OBSDIM / 4, 31, 0x7fffffff);            // obssb
    addseg(obs_W, WOBS_OFF, 512 * (OBSDIM / 4), 10, OBSOUT);              // padded 448->512
    for (int i = 0; i < NLAYERS; ++i)
        addseg(W_in + (size_t)i * 2 * DINNER * DMODEL, WIN_OFF + (size_t)i * 2 * MiB,
               2 * DINNER * DMODEL / 4, 31, 0x7fffffff);
    for (int i = 0; i < NLAYERS; ++i)
        addseg(W_out + (size_t)i * DMODEL * DINNER, WOUT_OFF + (size_t)i * MiB,
               DMODEL * DINNER / 4, 31, 0x7fffffff);
    for (int i = 0; i < NLAYERS; ++i)
        addseg(W_x + (size_t)i * 64 * DINNER, WX_OFF + (size_t)i * (MiB / 4),
               128 * (DINNER / 4), 8, 64);                                // padded 64->128
    addseg(ffn_W1, WF1_OFF, DMODEL * DMODEL / 4, 31, 0x7fffffff);
    cs.blk_start[si] = nb;
    cast_all_kernel<<<nb, 256, 0, stream>>>(cs, (char*)d_ws);

    embed_kernel<<<MROWS * ADIM / 256, 256, 0, stream>>>(actions, act_emb, pos_emb, xb);
    gemm_mfma<MEPI_TOK, 64><<<8 * (MROWS / 128), 256, 0, stream>>>(
        obssb, OBSDIM, (__hip_bfloat16*)(base + WOBS_OFF), nullptr, 0, xb, DMODEL,
        ADIM, OBSOUT, OBSDIM, 8, obs_b, pos_emb);

    for (int i = 0; i < NLAYERS; ++i) {
        // W_in: xzb = bf16(xb @ W_in^T), ld 2048 (xi | z)
        gemm_mfma<MEPI_BF16, 128><<<(2 * DINNER / 128) * (MROWS / 128), 256, 0, stream>>>(
            xb, DMODEL, (__hip_bfloat16*)(base + WIN_OFF + (size_t)i * 2 * MiB),
            nullptr, 0, xzb, 2 * DINNER, 0, 2 * DINNER, DMODEL,
            2 * DINNER / 128, nullptr, nullptr);
        conv_silu_kernel<<<MROWS * DINNER / 256, 256, 0, stream>>>(
            xzb, conv_w + (size_t)i * DINNER * 4, conv_b + (size_t)i * DINNER, xcb);
        // W_x: split-K=4 partials then combine into xdt (f32) + bcb (packed bf16)
        gemm_mfma<MEPI_PART, 64><<<256, 256, 0, stream>>>(
            xcb, DINNER, (__hip_bfloat16*)(base + WX_OFF + (size_t)i * (MiB / 4)),
            xdtp, 0, nullptr, 0, 0, 64, 256, 1, nullptr, nullptr);
        combine_split_kernel<<<MROWS * 16 / 256, 256, 0, stream>>>(xdtp, xdt, bcb);
        // W_dt (f32, K=32, softplus): dtb (bf16)
        gemm_f32_sp<<<dim3(DINNER / 64, MROWS / 64), 256, 0, stream>>>(
            xdt, 32, W_dt + (size_t)i * DINNER * DTRANK, dtb, DINNER, DINNER, DTRANK,
            b_dt + (size_t)i * DINNER);
        scan_kernel<<<(32 * DINNER) / 16, 256, 0, stream>>>(
            dtb, bcb, xcb, xzb + DINNER, A_log + (size_t)i * DINNER * DSTATE,
            D_p + (size_t)i * DINNER, yb);
        // W_out: xb = bf16(yb @ W_out^T)
        gemm_mfma<MEPI_BF16, 64><<<(DMODEL / 64) * (MROWS / 128), 256, 0, stream>>>(
            yb, DINNER, (__hip_bfloat16*)(base + WOUT_OFF + (size_t)i * MiB),
            nullptr, 0, xb, DMODEL, 0, DMODEL, DINNER,
            DMODEL / 64, nullptr, nullptr);
    }

    gemm_mfma<MEPI_RELUB, 64><<<(DMODEL / 64) * (MROWS / 128), 256, 0, stream>>>(
        xb, DMODEL, (__hip_bfloat16*)(base + WF1_OFF), nullptr, 0, hbuf, DMODEL,
        0, DMODEL, DMODEL, DMODEL / 64, ffn_b1, nullptr);
    ffn2_kernel<<<MROWS * 32 / 256, 256, 0, stream>>>(hbuf, ffn_W2, ffn_b2, out);
}

// Round 6
// 1101.730 us; speedup vs baseline: 1.1645x; 1.0060x over previous
//
#include <hip/hip_runtime.h>
#include <hip/hip_bf16.h>
#include <cstdint>
#include <cstddef>

#define HIST    256
#define DMODEL  512
#define DINNER  1024
#define DSTATE  16
#define DTRANK  32
#define OBSDIM  4096
#define OBSOUT  448
#define ADIM    64
#define NLAYERS 4
#define MROWS   8192   // BATCH*HIST

typedef __bf16  bf16x8 __attribute__((ext_vector_type(8)));
typedef float   f32x4  __attribute__((ext_vector_type(4)));

enum { MEPI_TOK = 0, MEPI_BF16 = 1, MEPI_SPLIT = 2, MEPI_RELUB = 3, MEPI_PART = 4, MEPI_PTOK = 5 };

__device__ __forceinline__ float siluf(float x) { return x / (1.f + __expf(-x)); }
__device__ __forceinline__ float softplusf(float x) {
    return fmaxf(x, 0.f) + log1pf(__expf(-fabsf(x)));
}
__device__ __forceinline__ float bflo(unsigned u) { return __uint_as_float(u << 16); }
__device__ __forceinline__ float bfhi(unsigned u) { return __uint_as_float(u & 0xffff0000u); }

// ---------------------------------------------------------------------------
// bf16 MFMA GEMM, 128xNW tile (NW = 128 or 64), BK=32, multi-buffer LDS.
// NW=64: 4 buffers, prefetch depth 3. NW=128: 3 buffers, depth 2 (48 KB both).
// wld = W leading dimension (row stride), decoupled from K so split-K kernels
// read the true weight rows. Split-K (PART: 4x256 over K=1024; PTOK: 2x2048
// over K=4096) offsets BOTH A and W by kc*chunk, so partial[kc][m][n] =
// <A chunk kc, W[n] chunk kc> and the flat sum over kc in the combine kernel
// is exact. (R3-R5's PART used K as the W stride — read wrong W rows; the
// pathway is numerically suppressed by b_dt=-4.6 so tests missed it. Fixed.)
template<int EPI, int NW>
__global__ __launch_bounds__(256)
void gemm_mfma(const __hip_bfloat16* __restrict__ A, int lda,
               const __hip_bfloat16* __restrict__ W,
               float* __restrict__ Cf, int ldc,
               __hip_bfloat16* __restrict__ Cb, int ldcb,
               int coff, int N, int K, int wld, int nbn,
               const float* __restrict__ bias, const float* __restrict__ pos)
{
    constexpr int MI   = (NW == 128) ? 4 : 2;   // 16-row fragments per wave (M dir)
    constexpr int NBUF = (NW == 128) ? 3 : 4;
    __shared__ __hip_bfloat16 Asm[NBUF][128 * 32];
    __shared__ __hip_bfloat16 Bsm[NBUF][NW * 32];
    const int bid = blockIdx.x;
    const int xcd = bid & 7;
    const int s   = bid >> 3;
    int n_blk, m_blk, kc_ = 0;
    if constexpr (EPI == MEPI_PART) {
        // grid == 256: 64 m-blocks x 4 k-chunks of 256
        m_blk = xcd * 8 + (s >> 2);
        kc_   = s & 3;
        n_blk = 0;
    } else if constexpr (EPI == MEPI_PTOK) {
        // grid == 512: 64 m-blocks x 4 n-blocks x 2 k-chunks of 2048
        m_blk = xcd * 8 + (s >> 3);
        n_blk = (s >> 1) & 3;
        kc_   = s & 1;
    } else {
        n_blk = s % nbn;
        m_blk = xcd * ((int)(gridDim.x >> 3) / nbn) + s / nbn;
    }
    const int m0 = m_blk * 128;
    const int n0 = n_blk * NW;
    const int kch = (EPI == MEPI_PART) ? kc_ * 256 : (EPI == MEPI_PTOK) ? kc_ * 2048 : 0;

    const int tid  = threadIdx.x;
    const int lane = tid & 63;
    const int wv   = tid >> 6;
    const int wm   = (NW == 128) ? ((wv >> 1) << 6) : (wv << 5);
    const int wn   = (NW == 128) ? ((wv & 1) << 6) : 0;
    const int sr   = lane >> 2;
    const int scs  = (((lane & 3) ^ ((lane >> 4) & 3)) << 3);  // pre-swizzled source chunk
    const int quad = lane >> 4;
    const int c16  = lane & 15;

    f32x4 acc[MI][4] = {};
    const __hip_bfloat16* aptr = A + (size_t)(m0 + wv * 16 + sr) * lda + scs + kch;
    const __hip_bfloat16* bptr = W + (size_t)(n0 + wv * 16 + sr) * wld + scs + kch;

#define STAGE(K0, BUF) { \
    __hip_bfloat16* asml = Asm[BUF] + wv * 16 * 32; \
    __hip_bfloat16* bsml = Bsm[BUF] + wv * 16 * 32; \
    __builtin_amdgcn_global_load_lds( \
        (const __attribute__((address_space(1))) void*)(aptr + (K0)), \
        (__attribute__((address_space(3))) void*)(asml), 16, 0, 0); \
    __builtin_amdgcn_global_load_lds( \
        (const __attribute__((address_space(1))) void*)(aptr + (size_t)64 * lda + (K0)), \
        (__attribute__((address_space(3))) void*)(asml + 64 * 32), 16, 0, 0); \
    __builtin_amdgcn_global_load_lds( \
        (const __attribute__((address_space(1))) void*)(bptr + (K0)), \
        (__attribute__((address_space(3))) void*)(bsml), 16, 0, 0); \
    if (NW == 128) \
        __builtin_amdgcn_global_load_lds( \
            (const __attribute__((address_space(1))) void*)(bptr + (size_t)64 * wld + (K0)), \
            (__attribute__((address_space(3))) void*)(bsml + 64 * 32), 16, 0, 0); \
    }

    auto kstep = [&](int buf) {
        __builtin_amdgcn_s_barrier();            // A: cur-tile loads visible to all
        __builtin_amdgcn_sched_barrier(0);
        bf16x8 af[MI], bfr[4];
        const int csw = ((quad ^ ((c16 >> 2) & 3)) << 3);
        #pragma unroll
        for (int i = 0; i < MI; ++i)
            af[i]  = *(const bf16x8*)(Asm[buf] + (wm + i * 16 + c16) * 32 + csw);
        #pragma unroll
        for (int j = 0; j < 4; ++j)
            bfr[j] = *(const bf16x8*)(Bsm[buf] + (wn + j * 16 + c16) * 32 + csw);
        #pragma unroll
        for (int i = 0; i < MI; ++i)
            #pragma unroll
            for (int j = 0; j < 4; ++j)
                acc[i][j] = __builtin_amdgcn_mfma_f32_16x16x32_bf16(af[i], bfr[j], acc[i][j], 0, 0, 0);
        __builtin_amdgcn_sched_barrier(0);
        __builtin_amdgcn_s_barrier();            // B: all reads done -> buffer reusable
    };

    const int NT = K >> 5;                        // all call sites have NT >= NBUF
    #pragma unroll
    for (int t = 0; t < NBUF - 1; ++t) STAGE(t << 5, t)
    int sb = NBUF - 1, cb = 0;
    int it = 0;
    for (; it + NBUF - 1 < NT; ++it) {
        STAGE((it + NBUF - 1) << 5, sb)
        sb = (sb + 1 == NBUF) ? 0 : sb + 1;
        if constexpr (NW == 128) asm volatile("s_waitcnt vmcnt(8)" ::: "memory");
        else                     asm volatile("s_waitcnt vmcnt(9)" ::: "memory");
        kstep(cb);
        cb = (cb + 1 == NBUF) ? 0 : cb + 1;
    }
    if constexpr (NW == 64) {   // depth-3 tail: 6, 3, 0
        asm volatile("s_waitcnt vmcnt(6)" ::: "memory");
        kstep(cb); cb = (cb + 1 == NBUF) ? 0 : cb + 1;
        asm volatile("s_waitcnt vmcnt(3)" ::: "memory");
        kstep(cb); cb = (cb + 1 == NBUF) ? 0 : cb + 1;
        asm volatile("s_waitcnt vmcnt(0)" ::: "memory");
        kstep(cb);
    } else {                    // depth-2 tail: 4, 0
        asm volatile("s_waitcnt vmcnt(4)" ::: "memory");
        kstep(cb); cb = (cb + 1 == NBUF) ? 0 : cb + 1;
        asm volatile("s_waitcnt vmcnt(0)" ::: "memory");
        kstep(cb);
    }
#undef STAGE

    #pragma unroll
    for (int i = 0; i < MI; ++i) {
        const int mbase = m0 + wm + i * 16 + quad * 4;
        #pragma unroll
        for (int j = 0; j < 4; ++j) {
            const int n = n0 + wn + j * 16 + c16;
            if (n < N) {
                #pragma unroll
                for (int r = 0; r < 4; ++r) {
                    const size_t m = mbase + r;
                    float v = acc[i][j][r];
                    if (EPI == MEPI_BF16) {
                        Cb[m * ldcb + n] = __float2bfloat16(v);
                    } else if (EPI == MEPI_SPLIT) {
                        if (n < DTRANK) Cf[m * 32 + n] = v;
                        else Cb[(m >> 1) * 64 + (n & 15) * 4 + (m & 1) * 2 + ((n >> 4) & 1)]
                                 = __float2bfloat16(v);
                    } else if (EPI == MEPI_PART) {
                        Cf[((size_t)kc_ * MROWS + m) * 64 + n] = v;
                    } else if (EPI == MEPI_PTOK) {
                        Cf[((size_t)kc_ * MROWS + m) * 512 + n] = v;
                    } else { // MEPI_RELUB
                        Cb[m * ldcb + n] = __float2bfloat16(fmaxf(v + bias[n], 0.f));
                    }
                }
            }
        }
    }
}

// sums the 4 W_x split-K partials; n<32 -> xdt (f32), n>=32 -> bcb (packed bf16)
__global__ __launch_bounds__(256)
void combine_split_kernel(const float* __restrict__ p, float* __restrict__ xdt,
                          __hip_bfloat16* __restrict__ bcb)
{
    const int idx = blockIdx.x * 256 + threadIdx.x;     // MROWS*16
    const int m  = idx >> 4;
    const int n4 = (idx & 15) << 2;
    const float4 a = *(const float4*)(p + (size_t)m * 64 + n4);
    const float4 b = *(const float4*)(p + ((size_t)MROWS + m) * 64 + n4);
    const float4 c = *(const float4*)(p + ((size_t)2 * MROWS + m) * 64 + n4);
    const float4 d = *(const float4*)(p + ((size_t)3 * MROWS + m) * 64 + n4);
    const float v[4] = { a.x + b.x + c.x + d.x, a.y + b.y + c.y + d.y,
                         a.z + b.z + c.z + d.z, a.w + b.w + c.w + d.w };
    if (n4 < 32) {
        *(float4*)(xdt + (size_t)m * 32 + n4) = make_float4(v[0], v[1], v[2], v[3]);
    } else {
        #pragma unroll
        for (int j = 0; j < 4; ++j) {
            const int n = n4 + j;
            bcb[(m >> 1) * 64 + (n & 15) * 4 + (m & 1) * 2 + ((n >> 4) & 1)]
                = __float2bfloat16(v[j]);
        }
    }
}

// sums the 2 TOK split-K partials + bias + pos, writes xb cols 64..511 (bf16)
__global__ __launch_bounds__(256)
void combine_tok_kernel(const float* __restrict__ p, const float* __restrict__ bias,
                        const float* __restrict__ pos, __hip_bfloat16* __restrict__ xb)
{
    const int stride = gridDim.x * 256;
    const int TOT = MROWS * (OBSOUT / 4);            // 112 float4 per row
    for (int g = blockIdx.x * 256 + (int)threadIdx.x; g < TOT; g += stride) {
        const int m  = g / (OBSOUT / 4);
        const int n4 = (g - m * (OBSOUT / 4)) * 4;   // 0..444
        const float4 a  = *(const float4*)(p + (size_t)m * 512 + n4);
        const float4 b  = *(const float4*)(p + ((size_t)MROWS + m) * 512 + n4);
        const int l = m & (HIST - 1);
        const float4 bs = *(const float4*)(bias + n4);
        const float4 ps = *(const float4*)(pos + (size_t)l * DMODEL + ADIM + n4);
        union { __hip_bfloat16 h[4]; short4 s; } o;
        o.h[0] = __float2bfloat16(a.x + b.x + bs.x + ps.x);
        o.h[1] = __float2bfloat16(a.y + b.y + bs.y + ps.y);
        o.h[2] = __float2bfloat16(a.z + b.z + bs.z + ps.z);
        o.h[3] = __float2bfloat16(a.w + b.w + bs.w + ps.w);
        *(short4*)(xb + (size_t)m * DMODEL + ADIM + n4) = o.s;
    }
}

// ---------------------------------------------------------------------------
// f32 GEMM for W_dt (K=32): dtb = bf16(softplus(xdt @ W_dt^T + b_dt))
__global__ __launch_bounds__(256)
void gemm_f32_sp(const float* __restrict__ A, int lda,
                 const float* __restrict__ W,
                 __hip_bfloat16* __restrict__ C, int ldc,
                 int N, int K, const float* __restrict__ bias)
{
    __shared__ float As[32][68];
    __shared__ float Ws[32][68];
    const int tid = threadIdx.x;
    const int tx = tid & 15, ty = tid >> 4;
    const int m0 = blockIdx.y * 64;
    const int n0 = blockIdx.x * 64;
    const int lr = tid >> 3;
    const int lc = (tid & 7) << 2;
    float acc[4][4] = {};
    for (int k0 = 0; k0 < K; k0 += 32) {
        const float4 a0 = *(const float4*)(A + (size_t)(m0 + lr) * lda + k0 + lc);
        const float4 a1 = *(const float4*)(A + (size_t)(m0 + lr + 32) * lda + k0 + lc);
        const float4 b0 = *(const float4*)(W + (size_t)(n0 + lr) * K + k0 + lc);
        const float4 b1 = *(const float4*)(W + (size_t)(n0 + lr + 32) * K + k0 + lc);
        __syncthreads();
        As[lc+0][lr] = a0.x; As[lc+1][lr] = a0.y; As[lc+2][lr] = a0.z; As[lc+3][lr] = a0.w;
        As[lc+0][lr+32] = a1.x; As[lc+1][lr+32] = a1.y; As[lc+2][lr+32] = a1.z; As[lc+3][lr+32] = a1.w;
        Ws[lc+0][lr] = b0.x; Ws[lc+1][lr] = b0.y; Ws[lc+2][lr] = b0.z; Ws[lc+3][lr] = b0.w;
        Ws[lc+0][lr+32] = b1.x; Ws[lc+1][lr+32] = b1.y; Ws[lc+2][lr+32] = b1.z; Ws[lc+3][lr+32] = b1.w;
        __syncthreads();
        #pragma unroll
        for (int k = 0; k < 32; ++k) {
            const float4 a4 = *(const float4*)&As[k][ty << 2];
            const float4 b4 = *(const float4*)&Ws[k][tx << 2];
            const float a[4] = {a4.x, a4.y, a4.z, a4.w};
            const float b[4] = {b4.x, b4.y, b4.z, b4.w};
            #pragma unroll
            for (int i = 0; i < 4; ++i)
                #pragma unroll
                for (int j = 0; j < 4; ++j)
                    acc[i][j] = fmaf(a[i], b[j], acc[i][j]);
        }
    }
    const int mb = m0 + (ty << 2);
    const int nb = n0 + (tx << 2);
    #pragma unroll
    for (int i = 0; i < 4; ++i) {
        const size_t m = mb + i;
        #pragma unroll
        for (int j = 0; j < 4; ++j) {
            const int n = nb + j;
            C[m * ldc + n] = __float2bfloat16(softplusf(acc[i][j] + bias[n]));
        }
    }
}

// ---------------------------------------------------------------------------
// One consolidated grid-stride cast kernel: all f32 -> bf16 staging in a
// single persistent launch (R5's one-element-per-block version hit only
// 2.2 TB/s from block churn + zero MLP). Segment found by linear scan over
// flat float4 index; segment 0 (obss) is the bulk so the scan is ~1 compare.
#define NSEG 15
struct CastSegs {
    const float* src[NSEG];
    unsigned long long dstoff[NSEG];   // byte offset into workspace
    int el_start[NSEG + 1];            // flat float4 start of each segment
    int shift[NSEG];
    int nrows[NSEG];
};

__global__ __launch_bounds__(256)
void cast_all_kernel(CastSegs cs, char* wsbase, int total4)
{
    const int stride = gridDim.x * 256;
    for (int g = blockIdx.x * 256 + (int)threadIdx.x; g < total4; g += stride) {
        int s = 0;
        #pragma unroll 1
        while (s < NSEG - 1 && g >= cs.el_start[s + 1]) ++s;
        const int i = g - cs.el_start[s];
        const int row = i >> cs.shift[s];
        float4 v = make_float4(0.f, 0.f, 0.f, 0.f);
        if (row < cs.nrows[s]) v = ((const float4*)cs.src[s])[i];
        union { __hip_bfloat16 h[4]; short4 sh; } o;
        o.h[0] = __float2bfloat16(v.x); o.h[1] = __float2bfloat16(v.y);
        o.h[2] = __float2bfloat16(v.z); o.h[3] = __float2bfloat16(v.w);
        ((short4*)(wsbase + cs.dstoff[s]))[i] = o.sh;
    }
}

__global__ __launch_bounds__(256)
void embed_kernel(const int* __restrict__ actions, const float* __restrict__ act_emb,
                  const float* __restrict__ pos_emb, __hip_bfloat16* __restrict__ xb)
{
    const int idx = blockIdx.x * 256 + threadIdx.x;   // MROWS*64
    const int e = idx & 63;
    const int m = idx >> 6;
    const int l = m & (HIST - 1);
    const int b = m >> 8;
    float v = pos_emb[l * DMODEL + e];
    if (l > 0) {
        const int a = actions[b * HIST + l - 1];
        v += act_emb[a * ADIM + e];
    }
    xb[(size_t)m * DMODEL + e] = __float2bfloat16(v);
}

// xcb[m,d] = bf16(silu(conv_b[d] + sum_k conv_w[d,k]*xi[l-3+k, d]))
__global__ __launch_bounds__(256)
void conv_silu_kernel(const __hip_bfloat16* __restrict__ xzb, const float* __restrict__ cw,
                      const float* __restrict__ cb, __hip_bfloat16* __restrict__ xcb)
{
    const int idx = blockIdx.x * 256 + threadIdx.x;   // MROWS*DINNER
    const int d = idx & (DINNER - 1);
    const int m = idx >> 10;
    const int l = m & (HIST - 1);
    const float4 w = ((const float4*)cw)[d];
    const __hip_bfloat16* basep = xzb + (size_t)m * (2 * DINNER) + d;
    float acc = cb[d] + w.w * __bfloat162float(basep[0]);
    if (l >= 1) acc = fmaf(w.z, __bfloat162float(basep[-2 * DINNER]), acc);
    if (l >= 2) acc = fmaf(w.y, __bfloat162float(basep[-4 * DINNER]), acc);
    if (l >= 3) acc = fmaf(w.x, __bfloat162float(basep[-6 * DINNER]), acc);
    xcb[idx] = __float2bfloat16(siluf(acc));
}

// ---------------------------------------------------------------------------
// Selective scan v5: chunked double-buffered staging, transposed LDS,
// z register prefetch, XCD swizzle, exp2-folded A, fused single-instruction
// DPP butterfly adds (v_add_f32_dpp).
#define DPPA(x, CTRL) { float _t; \
    asm("v_add_f32_dpp %0, %1, %1 " CTRL " row_mask:0xf bank_mask:0xf" \
        : "=v"(_t) : "v"(x)); x = _t; }

__global__ __launch_bounds__(256)
void scan_kernel(const __hip_bfloat16* __restrict__ dtb, const __hip_bfloat16* __restrict__ bcb,
                 const __hip_bfloat16* __restrict__ xcb, const __hip_bfloat16* __restrict__ zb,
                 const float* __restrict__ A_log, const float* __restrict__ D_p,
                 __hip_bfloat16* __restrict__ yb)
{
    // [buf][channel 16][step 64 + pad4] u32 {dt lo16, xc hi16} / {B lo16, C hi16}
    __shared__ unsigned sdx[2][16][68];
    __shared__ unsigned sbc[2][16][68];

    const int tid = threadIdx.x;
    const int n   = tid & 15;     // state
    const int g   = tid >> 4;     // channel within block

    const int bid = blockIdx.x;
    const int blk = ((bid & 7) << 8) | (bid >> 3);
    const int c0  = blk * 16;
    const int b   = c0 >> 10;
    const int d0  = c0 & (DINNER - 1);
    const int d   = d0 + g;
    const size_t row0 = (size_t)b * HIST;

    const int sr = tid >> 2;
    const int sq = tid & 3;
    const unsigned short* dtu = (const unsigned short*)dtb;
    const unsigned short* xcu = (const unsigned short*)xcb;
    const unsigned short* zu  = (const unsigned short*)zb;
    const unsigned*       bcu = (const unsigned*)bcb;

    const float Ar = -__expf(A_log[d * DSTATE + n]);
#if __has_builtin(__builtin_amdgcn_exp2f)
    const float A2 = Ar * 1.44269504089f;
#define DAEXP(x) __builtin_amdgcn_exp2f((x) * A2)
#else
#define DAEXP(x) __expf((x) * Ar)
#endif
    const float Dp = D_p[d];
    float h = 0.f;

    uint2 dv, xv; uint4 bv;
    unsigned short za[4], znx[4];

#define SLOAD(cc) { \
    const size_t rb = (row0 + (size_t)(cc) * 64 + sr) * DINNER + d0 + sq * 4; \
    dv = *(const uint2*)(dtu + rb); \
    xv = *(const uint2*)(xcu + rb); \
    bv = *(const uint4*)(bcu + row0 * 16 + (size_t)(cc) * 1024 + tid * 4); \
}
#define SWRITE(bb) { \
    const int ch = sq * 4; \
    sdx[bb][ch + 0][sr] = (dv.x & 0xffffu) | (xv.x << 16); \
    sdx[bb][ch + 1][sr] = (dv.x >> 16)     | (xv.x & 0xffff0000u); \
    sdx[bb][ch + 2][sr] = (dv.y & 0xffffu) | (xv.y << 16); \
    sdx[bb][ch + 3][sr] = (dv.y >> 16)     | (xv.y & 0xffff0000u); \
    const int e2 = (tid & 7) * 2, p2 = (tid >> 3) * 2; \
    sbc[bb][e2 + 0][p2 + 0] = bv.x; \
    sbc[bb][e2 + 0][p2 + 1] = bv.y; \
    sbc[bb][e2 + 1][p2 + 0] = bv.z; \
    sbc[bb][e2 + 1][p2 + 1] = bv.w; \
}
#define ZLOAD(cc, arr) { \
    _Pragma("unroll") \
    for (int w = 0; w < 4; ++w) \
        arr[w] = zu[(row0 + (size_t)(cc) * 64 + w * 16 + n) * (2 * DINNER) + d0 + g]; \
}
#define SSTEP(Q, R, KK) { \
    const float dt = bflo(Q), xc = bfhi(Q); \
    const float Bv = bflo(R), Cv = bfhi(R); \
    const float dA = DAEXP(dt); \
    h = fmaf(dA, h, dt * xc * Bv); \
    float ctr = h * Cv; \
    DPPA(ctr, "quad_perm:[1,0,3,2]") \
    DPPA(ctr, "quad_perm:[2,3,0,1]") \
    DPPA(ctr, "row_half_mirror") \
    DPPA(ctr, "row_mirror") \
    if (n == (KK)) yreg = ctr; \
}

    SLOAD(0)
    ZLOAD(0, za)
    SWRITE(0)
    __syncthreads();

    for (int c = 0; c < 4; ++c) {
        const int buf = c & 1;
        if (c < 3) { SLOAD(c + 1) ZLOAD(c + 1, znx) }   // issue early (T14)

        const unsigned (*sdxc)[68] = sdx[buf];
        const unsigned (*sbcc)[68] = sbc[buf];
        #pragma unroll
        for (int w = 0; w < 4; ++w) {
            float yreg = 0.f;
            #pragma unroll
            for (int jq = 0; jq < 4; ++jq) {
                const uint4 qv = *(const uint4*)&sdxc[g][w * 16 + jq * 4];
                const uint4 rv = *(const uint4*)&sbcc[n][w * 16 + jq * 4];
                SSTEP(qv.x, rv.x, jq * 4 + 0)
                SSTEP(qv.y, rv.y, jq * 4 + 1)
                SSTEP(qv.z, rv.z, jq * 4 + 2)
                SSTEP(qv.w, rv.w, jq * 4 + 3)
            }
            const float xcf = bfhi(sdxc[g][w * 16 + n]);
            const float ze  = __uint_as_float((unsigned)za[w] << 16);
            yb[(row0 + c * 64 + w * 16 + n) * DINNER + d] =
                __float2bfloat16((yreg + xcf * Dp) * siluf(ze));
        }

        if (c < 3) SWRITE((c + 1) & 1)   // write late, after compute covered latency
        __syncthreads();
        #pragma unroll
        for (int w = 0; w < 4; ++w) za[w] = znx[w];
    }
#undef SLOAD
#undef SWRITE
#undef ZLOAD
#undef SSTEP
#undef DAEXP
}

// out[m,n] = b2[n] + sum_k h[m,k]*W2[n,k]  (h in bf16)
__global__ __launch_bounds__(256)
void ffn2_kernel(const __hip_bfloat16* __restrict__ h, const float* __restrict__ W2,
                 const float* __restrict__ b2, float* __restrict__ out)
{
    const int idx = blockIdx.x * 256 + threadIdx.x;   // MROWS*32
    const int n = idx & 31;
    const int m = idx >> 5;
    if (n >= 18) return;
    const unsigned short* hr = (const unsigned short*)(h + (size_t)m * DMODEL);
    const float* wr = W2 + (size_t)n * DMODEL;
    float acc = b2[n];
    for (int k = 0; k < DMODEL; k += 8) {
        const uint4 hv = *(const uint4*)(hr + k);
        const float4 w0 = *(const float4*)(wr + k);
        const float4 w1 = *(const float4*)(wr + k + 4);
        acc = fmaf(bflo(hv.x), w0.x, acc);
        acc = fmaf(bfhi(hv.x), w0.y, acc);
        acc = fmaf(bflo(hv.y), w0.z, acc);
        acc = fmaf(bfhi(hv.y), w0.w, acc);
        acc = fmaf(bflo(hv.z), w1.x, acc);
        acc = fmaf(bfhi(hv.z), w1.y, acc);
        acc = fmaf(bflo(hv.w), w1.z, acc);
        acc = fmaf(bfhi(hv.w), w1.w, acc);
    }
    out[(size_t)m * 18 + n] = acc;
}

extern "C" void kernel_launch(void* const* d_in, const int* in_sizes, int n_in,
                              void* d_out, int out_size, void* d_ws, size_t ws_size,
                              hipStream_t stream)
{
    const float* obss    = (const float*)d_in[0];
    const int*   actions = (const int*)  d_in[1];
    const float* obs_W   = (const float*)d_in[2];
    const float* obs_b   = (const float*)d_in[3];
    const float* act_emb = (const float*)d_in[4];
    const float* pos_emb = (const float*)d_in[5];
    const float* W_in    = (const float*)d_in[6];
    const float* conv_w  = (const float*)d_in[7];
    const float* conv_b  = (const float*)d_in[8];
    const float* W_x     = (const float*)d_in[9];
    const float* W_dt    = (const float*)d_in[10];
    const float* b_dt    = (const float*)d_in[11];
    const float* A_log   = (const float*)d_in[12];
    const float* D_p     = (const float*)d_in[13];
    const float* W_out   = (const float*)d_in[14];
    const float* ffn_W1  = (const float*)d_in[15];
    const float* ffn_b1  = (const float*)d_in[16];
    const float* ffn_W2  = (const float*)d_in[17];
    const float* ffn_b2  = (const float*)d_in[18];
    float* out = (float*)d_out;

    const size_t MiB = 1024 * 1024;
    char* base = (char*)d_ws;
    __hip_bfloat16* xb    = (__hip_bfloat16*)(base);
    __hip_bfloat16* xzb   = (__hip_bfloat16*)(base + 8 * MiB);
    __hip_bfloat16* xcb   = (__hip_bfloat16*)(base + 40 * MiB);
    __hip_bfloat16* dtb   = (__hip_bfloat16*)(base + 56 * MiB);
    __hip_bfloat16* yb    = (__hip_bfloat16*)(base + 88 * MiB);
    float*          xdt   = (float*)(base + 104 * MiB);
    __hip_bfloat16* bcb   = (__hip_bfloat16*)(base + 105 * MiB);
    float*          xdtp  = (float*)(base + 112 * MiB);          // 4 x 2 MiB W_x split-K partials
    __hip_bfloat16* obssb = (__hip_bfloat16*)(base + 8 * MiB);   // dead after TOK gemm
    __hip_bfloat16* hbuf  = (__hip_bfloat16*)(base + 8 * MiB);   // live only after last scan
    // persistent bf16 weight slots (cast once per iteration, one launch)
    const size_t WOBS_OFF = 128 * MiB;                           // 512x4096 (padded)
    const size_t WIN_OFF  = 132 * MiB;                           // 4 x 2 MiB
    const size_t WOUT_OFF = 140 * MiB;                           // 4 x 1 MiB
    const size_t WX_OFF   = 144 * MiB;                           // 4 x 0.25 MiB (padded)
    const size_t WF1_OFF  = 145 * MiB;                           // 0.5 MiB
    float*          tokp  = (float*)(base + 160 * MiB);          // 2 x 16 MiB TOK split-K partials

    // --- one consolidated grid-stride cast launch ---
    CastSegs cs{};
    int nel = 0, si = 0;
    auto addseg = [&](const float* src, size_t dstoff, int n4, int shift, int nrows) {
        cs.src[si] = src; cs.dstoff[si] = dstoff;
        cs.shift[si] = shift; cs.nrows[si] = nrows;
        cs.el_start[si] = nel; nel += n4; ++si;
    };
    addseg(obss, 8 * MiB, MROWS * OBSDIM / 4, 31, 0x7fffffff);            // obssb (bulk, first)
    addseg(obs_W, WOBS_OFF, 512 * (OBSDIM / 4), 10, OBSOUT);              // padded 448->512
    for (int i = 0; i < NLAYERS; ++i)
        addseg(W_in + (size_t)i * 2 * DINNER * DMODEL, WIN_OFF + (size_t)i * 2 * MiB,
               2 * DINNER * DMODEL / 4, 31, 0x7fffffff);
    for (int i = 0; i < NLAYERS; ++i)
        addseg(W_out + (size_t)i * DMODEL * DINNER, WOUT_OFF + (size_t)i * MiB,
               DMODEL * DINNER / 4, 31, 0x7fffffff);
    for (int i = 0; i < NLAYERS; ++i)
        addseg(W_x + (size_t)i * 64 * DINNER, WX_OFF + (size_t)i * (MiB / 4),
               128 * (DINNER / 4), 8, 64);                                // padded 64->128
    addseg(ffn_W1, WF1_OFF, DMODEL * DMODEL / 4, 31, 0x7fffffff);
    cs.el_start[si] = nel;
    cast_all_kernel<<<2048, 256, 0, stream>>>(cs, (char*)d_ws, nel);

    embed_kernel<<<MROWS * ADIM / 256, 256, 0, stream>>>(actions, act_emb, pos_emb, xb);
    // TOK: split-K=2, NW=128 (grid 512, m97-class per-step efficiency)
    gemm_mfma<MEPI_PTOK, 128><<<512, 256, 0, stream>>>(
        obssb, OBSDIM, (const __hip_bfloat16*)(base + WOBS_OFF), tokp, 0, nullptr, 0,
        0, 512, 2048, OBSDIM, 1, nullptr, nullptr);
    combine_tok_kernel<<<1024, 256, 0, stream>>>(tokp, obs_b, pos_emb, xb);

    for (int i = 0; i < NLAYERS; ++i) {
        // W_in: xzb = bf16(xb @ W_in^T), ld 2048 (xi | z)
        gemm_mfma<MEPI_BF16, 128><<<(2 * DINNER / 128) * (MROWS / 128), 256, 0, stream>>>(
            xb, DMODEL, (const __hip_bfloat16*)(base + WIN_OFF + (size_t)i * 2 * MiB),
            nullptr, 0, xzb, 2 * DINNER, 0, 2 * DINNER, DMODEL, DMODEL,
            2 * DINNER / 128, nullptr, nullptr);
        conv_silu_kernel<<<MROWS * DINNER / 256, 256, 0, stream>>>(
            xzb, conv_w + (size_t)i * DINNER * 4, conv_b + (size_t)i * DINNER, xcb);
        // W_x: split-K=4 partials (per-chunk W offsets) then combine
        gemm_mfma<MEPI_PART, 64><<<256, 256, 0, stream>>>(
            xcb, DINNER, (const __hip_bfloat16*)(base + WX_OFF + (size_t)i * (MiB / 4)),
            xdtp, 0, nullptr, 0, 0, 64, 256, DINNER, 1, nullptr, nullptr);
        combine_split_kernel<<<MROWS * 16 / 256, 256, 0, stream>>>(xdtp, xdt, bcb);
        // W_dt (f32, K=32, softplus): dtb (bf16)
        gemm_f32_sp<<<dim3(DINNER / 64, MROWS / 64), 256, 0, stream>>>(
            xdt, 32, W_dt + (size_t)i * DINNER * DTRANK, dtb, DINNER, DINNER, DTRANK,
            b_dt + (size_t)i * DINNER);
        scan_kernel<<<(32 * DINNER) / 16, 256, 0, stream>>>(
            dtb, bcb, xcb, xzb + DINNER, A_log + (size_t)i * DINNER * DSTATE,
            D_p + (size_t)i * DINNER, yb);
        // W_out: xb = bf16(yb @ W_out^T)
        gemm_mfma<MEPI_BF16, 64><<<(DMODEL / 64) * (MROWS / 128), 256, 0, stream>>>(
            yb, DINNER, (const __hip_bfloat16*)(base + WOUT_OFF + (size_t)i * MiB),
            nullptr, 0, xb, DMODEL, 0, DMODEL, DINNER, DINNER,
            DMODEL / 64, nullptr, nullptr);
    }

    gemm_mfma<MEPI_RELUB, 64><<<(DMODEL / 64) * (MROWS / 128), 256, 0, stream>>>(
        xb, DMODEL, (const __hip_bfloat16*)(base + WF1_OFF), nullptr, 0, hbuf, DMODEL,
        0, DMODEL, DMODEL, DMODEL, DMODEL / 64, ffn_b1, nullptr);
    ffn2_kernel<<<MROWS * 32 / 256, 256, 0, stream>>>(hbuf, ffn_W2, ffn_b2, out);
}